// Round 7
// baseline (7302.746 us; speedup 1.0000x reference)
//
#include <hip/hip_runtime.h>
#include <hip/hip_bf16.h>
#include <math.h>

#define BB 32
#define TT 4096
#define DD 128
#define HH 4
#define dh 32
#define VV 33
#define LL 4
#define MM (BB*TT)   // 131072 rows
#define NCHUNK (MM/128)  // 1024
#define NC 64        // delta chunks per (b,h): TT/64

typedef short short8 __attribute__((ext_vector_type(8)));
typedef float f32x4 __attribute__((ext_vector_type(4)));

__device__ __forceinline__ float b2f(unsigned short u){
  union{float f; unsigned int x;} v; v.x = ((unsigned int)u)<<16; return v.f;
}
__device__ __forceinline__ unsigned short f2b(float f){
  union{float f; unsigned int x;} v; v.f=f;
  unsigned int r = v.x + 0x7fffu + ((v.x>>16)&1u);
  return (unsigned short)(r>>16);
}
__device__ __forceinline__ float blo(unsigned int u){ union{float f;unsigned int x;}v; v.x=u<<16; return v.f;}
__device__ __forceinline__ float bhi(unsigned int u){ union{float f;unsigned int x;}v; v.x=u&0xffff0000u; return v.f;}
__device__ __forceinline__ float siluf(float x){ return x/(1.0f+expf(-x)); }

// ---------------- embedding ----------------
__global__ __launch_bounds__(256) void k_embed(const int* __restrict__ x, const float* __restrict__ emb,
                                               float* __restrict__ h){
  int i = blockIdx.x*256 + threadIdx.x;
  int bt = i>>7, c = i&127;
  h[i] = emb[x[bt]*DD + c];
}

// ---------------- rms norm ----------------
__global__ __launch_bounds__(256) void k_rms(const float* __restrict__ src, const float* __restrict__ w,
                                             unsigned short* __restrict__ dst){
  int row = blockIdx.x*4 + (threadIdx.x>>6);
  int lane = threadIdx.x&63;
  const float2 xv = *(const float2*)(src + (size_t)row*DD + lane*2);
  float ss = xv.x*xv.x + xv.y*xv.y;
  #pragma unroll
  for (int m=1;m<64;m<<=1) ss += __shfl_xor(ss,m,64);
  float sc = rsqrtf(ss*(1.0f/128.0f)+1e-5f);
  const float2 wv = *(const float2*)(w + lane*2);
  unsigned int o = ((unsigned int)f2b(xv.y*sc*wv.y)<<16) | (unsigned int)f2b(xv.x*sc*wv.x);
  *(unsigned int*)(dst + (size_t)row*DD + lane*2) = o;
}

// ---------------- MFMA GEMM: out[M,N] = A[M,K] @ W[N,K]^T ----------------
template<int ACT, int OUTADD>
__global__ __launch_bounds__(256) void k_gemm(const unsigned short* __restrict__ A,
                                              const float* __restrict__ W,
                                              void* __restrict__ outp, int N, int K){
  __shared__ __align__(16) unsigned short As[128*128];
  __shared__ __align__(16) unsigned short Ws[64*128];
  const int tid = threadIdx.x;
  const int lane = tid & 63, wave = tid >> 6;
  const int row0 = blockIdx.x*128, col0 = blockIdx.y*64;
  const int wr0 = (wave&1)*64, wc0 = (wave>>1)*32;
  const int fr = lane & 15, fq = lane >> 4;
  f32x4 acc[4][2];
  #pragma unroll
  for (int m=0;m<4;m++){
    #pragma unroll
    for (int n=0;n<2;n++) acc[m][n] = (f32x4){0.f,0.f,0.f,0.f};
  }

  for (int kc=0; kc<K; kc+=128){
    #pragma unroll
    for (int ii=0; ii<8; ++ii){
      int flat = tid + ii*256;
      int r = flat>>4, g = flat&15;
      uint4 gv = *(const uint4*)(A + (size_t)(row0+r)*K + kc + g*8);
      *(uint4*)&As[r*128 + ((g^(r&7))<<3)] = gv;
    }
    #pragma unroll
    for (int ii=0; ii<8; ++ii){
      int flat = tid + ii*256;
      int n = flat>>5, q4 = flat&31;
      float4 wv = *(const float4*)(W + (size_t)(col0+n)*K + kc + q4*4);
      uint2 pk;
      pk.x = (unsigned int)f2b(wv.x) | ((unsigned int)f2b(wv.y)<<16);
      pk.y = (unsigned int)f2b(wv.z) | ((unsigned int)f2b(wv.w)<<16);
      int dst = n*128 + ((((q4>>1)^(n&7))<<3) | ((q4&1)<<2));
      *(uint2*)&Ws[dst] = pk;
    }
    __syncthreads();
    #pragma unroll
    for (int ks=0; ks<4; ++ks){
      int gg = ks*4 + fq;
      short8 a[4], b[2];
      #pragma unroll
      for (int m=0;m<4;m++){
        int row = wr0 + m*16 + fr;
        a[m] = *(const short8*)&As[row*128 + ((gg^(row&7))<<3)];
      }
      #pragma unroll
      for (int n=0;n<2;n++){
        int col = wc0 + n*16 + fr;
        b[n] = *(const short8*)&Ws[col*128 + ((gg^(col&7))<<3)];
      }
      #pragma unroll
      for (int m=0;m<4;m++){
        #pragma unroll
        for (int n=0;n<2;n++)
          acc[m][n] = __builtin_amdgcn_mfma_f32_16x16x32_bf16(a[m], b[n], acc[m][n], 0, 0, 0);
      }
    }
    __syncthreads();
  }

  if (OUTADD){
    float* O = (float*)outp;
    #pragma unroll
    for (int m=0;m<4;m++){
      #pragma unroll
      for (int n=0;n<2;n++){
        int ccol = col0 + wc0 + n*16 + fr;
        #pragma unroll
        for (int r=0;r<4;r++){
          int rrow = row0 + wr0 + m*16 + fq*4 + r;
          O[(size_t)rrow*N + ccol] += acc[m][n][r];
        }
      }
    }
  } else {
    unsigned short* O = (unsigned short*)outp;
    #pragma unroll
    for (int m=0;m<4;m++){
      #pragma unroll
      for (int n=0;n<2;n++){
        int ccol = col0 + wc0 + n*16 + fr;
        #pragma unroll
        for (int r=0;r<4;r++){
          int rrow = row0 + wr0 + m*16 + fq*4 + r;
          float vv = acc[m][n][r];
          if (ACT) vv = siluf(vv);
          O[(size_t)rrow*N + ccol] = f2b(vv);
        }
      }
    }
  }
}

// ---------------- beta = sigmoid(hn @ bw^T), N=4 ----------------
__global__ __launch_bounds__(256) void k_beta(const unsigned short* __restrict__ hn,
                                              const float* __restrict__ bwl, float* __restrict__ beta){
  __shared__ unsigned short As[64*128];
  int tid = threadIdx.x; int row0 = blockIdx.x*64;
  #pragma unroll
  for (int ii=0;ii<4;ii++){
    int flat = tid + ii*256;
    int r = flat>>4, v16 = flat&15;
    *(uint4*)&As[r*128 + v16*8] = *(const uint4*)(hn + (size_t)(row0+r)*DD + v16*8);
  }
  __syncthreads();
  int r = tid>>2, n = tid&3;
  const float* wr = bwl + n*DD;
  const unsigned short* ar = &As[r*128];
  float s = 0.f;
  #pragma unroll
  for (int k=0;k<128;k+=8){
    uint4 a = *(const uint4*)(ar + k);
    float4 wa = *(const float4*)(wr + k);
    float4 wb = *(const float4*)(wr + k + 4);
    s += blo(a.x)*wa.x + bhi(a.x)*wa.y + blo(a.y)*wa.z + bhi(a.y)*wa.w;
    s += blo(a.z)*wb.x + bhi(a.z)*wb.y + blo(a.w)*wb.z + bhi(a.w)*wb.w;
  }
  beta[(size_t)(row0+r)*HH + n] = 1.0f/(1.0f+expf(-s));
}

// ---------------- halo save ----------------
__global__ __launch_bounds__(256) void k_halo(const unsigned short* __restrict__ A,
                                              const unsigned short* __restrict__ B,
                                              const unsigned short* __restrict__ C,
                                              unsigned short* __restrict__ halo){
  int i = blockIdx.x*256 + threadIdx.x;
  int ch = i & 127;
  int rt = i >> 7;
  int r3 = rt % 3;
  int tn = (rt/3) % 3;
  int ck = rt / 9;
  unsigned short v = 0;
  if ((ck & 31) != 0){
    const unsigned short* X = (tn==0) ? A : (tn==1) ? B : C;
    v = X[((size_t)ck*128 - 3 + r3)*DD + ch];
  }
  halo[(size_t)i] = v;
}

// ---------------- in-place causal conv(4)+silu(+l2n) ----------------
__global__ __launch_bounds__(256) void k_conv_ip(
    unsigned short* __restrict__ A, unsigned short* __restrict__ B, unsigned short* __restrict__ C,
    const float* __restrict__ qcw, const float* __restrict__ qcb,
    const float* __restrict__ kcw, const float* __restrict__ kcb,
    const float* __restrict__ vcw, const float* __restrict__ vcb,
    const unsigned short* __restrict__ halo){
  __shared__ __align__(16) unsigned short Xs[131*128];
  const int tid = threadIdx.x;
  const int ck = blockIdx.x, tn = blockIdx.y;
  unsigned short* X = (tn==0) ? A : (tn==1) ? B : C;
  const float* w = (tn==0) ? qcw : (tn==1) ? kcw : vcw;
  const float* bi = (tn==0) ? qcb : (tn==1) ? kcb : vcb;

  if (tid < 48){
    int lr = tid>>4, c16 = tid&15;
    *(uint4*)&Xs[lr*128 + c16*8] = *(const uint4*)&halo[((size_t)(ck*3+tn)*3 + lr)*128 + c16*8];
  }
  #pragma unroll
  for (int ii=0; ii<8; ++ii){
    int flat = tid + ii*256;
    int r = flat>>4, c16 = flat&15;
    *(uint4*)&Xs[(3+r)*128 + c16*8] = *(const uint4*)&X[((size_t)ck*128 + r)*DD + c16*8];
  }
  __syncthreads();

  const int rh = tid>>7, c = tid&127;
  float w0=w[c*4+0], w1=w[c*4+1], w2=w[c*4+2], w3=w[c*4+3];
  float bc = bi[c];
  #pragma unroll 2
  for (int rr=0; rr<64; ++rr){
    int row = rr*2 + rh;
    float y = bc + w0*b2f(Xs[(row+0)*128+c]) + w1*b2f(Xs[(row+1)*128+c])
                 + w2*b2f(Xs[(row+2)*128+c]) + w3*b2f(Xs[(row+3)*128+c]);
    y = siluf(y);
    if (tn < 2){
      float s = y*y;
      #pragma unroll
      for (int m=1;m<32;m<<=1) s += __shfl_xor(s,m,64);
      y *= rsqrtf(s + 1e-6f);
      if (tn==0) y *= 0.17677669529663687f;
    }
    X[((size_t)ck*128 + row)*DD + c] = f2b(y);
  }
}

// ======================= chunked delta-rule (WY form) =======================
// chunk C=64, per (b,h): M = I + stril(diag(beta) K K^T, -1)
// W = M^-1 B V, U = M^-1 B K  (phase A, parallel over 8192 chunks)
// E_c = W_c - U_c S ; S += K_c^T E_c  (phase B, serial over 64 chunks, 128 blocks)
// O = Q S_entry + tril(Q K^T, incl diag) E   (phase C, parallel)
// v-layout: elem(b,t,h,d) = (b*TT+t)*128 + h*32 + d

// ---- phase A (v2): column-sweep forward substitution, history in registers ----
// Abt[s][t] = Ab[t][s] = beta_t*(k_t.k_s), stored transposed so step t reads a
// contiguous row (broadcast float4). racc[64] in VGPRs, fully unrolled.
__global__ __launch_bounds__(64) void k_pA(const unsigned short* __restrict__ kbuf,
                                           unsigned short* vwbuf,
                                           const float* __restrict__ betab,
                                           unsigned short* __restrict__ Ubuf){
  __shared__ float Abt[64][68];   // [s][t], row stride 68 floats (272B, 16B aligned)
  __shared__ float bs[64];
  const int c = blockIdx.x, bh = blockIdx.y;
  const int b = bh>>2, h = bh&3;
  const int lane = threadIdx.x;
  const int fr = lane&15, fg = lane>>4;
  const size_t base = ((size_t)b*TT + c*64)*128 + h*32;
  const size_t bbase = ((size_t)b*TT + c*64)*4 + h;

  bs[lane] = betab[bbase + (size_t)lane*4];

  short8 kf[4];
  #pragma unroll
  for (int mt=0;mt<4;mt++)
    kf[mt] = *(const short8*)(kbuf + base + (size_t)(mt*16+fr)*128 + fg*8);

  // Abt[s][t] for lower tiles (tile(t) >= tile(s)); diag tile written full (extra
  // entries are finite valid numbers, only multiplied into dead accumulators).
  #pragma unroll
  for (int mt=0;mt<4;mt++){
    float4 bsv = *(const float4*)&bs[mt*16 + fg*4];
    #pragma unroll
    for (int nt=0;nt<4;nt++){
      if (nt>mt) continue;
      f32x4 a = (f32x4){0.f,0.f,0.f,0.f};
      a = __builtin_amdgcn_mfma_f32_16x16x32_bf16(kf[mt], kf[nt], a, 0,0,0);
      #pragma unroll
      for (int r=0;r<4;r++){
        int t = mt*16 + fg*4 + r;
        float bt = (r==0)?bsv.x:(r==1)?bsv.y:(r==2)?bsv.z:bsv.w;
        Abt[nt*16+fr][t] = a[r]*bt;
      }
    }
  }

  // init: racc[t] = x_t * beta_t   (lane<32 -> V column lane, lane>=32 -> K column lane-32)
  const unsigned short* xp = ((lane<32)? (const unsigned short*)vwbuf : kbuf) + base + (lane&31);
  float racc[64];
  #pragma unroll
  for (int t=0;t<64;t++) racc[t] = b2f(xp[(size_t)t*128]) * bs[t];

  const size_t ub = ((size_t)bh*NC + c)*2048;
  #pragma unroll
  for (int t=0;t<64;t++){
    float w = racc[t];
    float nb = __shfl_down(w, 1, 64);
    if ((lane&1)==0){
      unsigned int pk = (unsigned int)f2b(w) | ((unsigned int)f2b(nb)<<16);
      if (lane<32) *(unsigned int*)(vwbuf + base + (size_t)t*128 + lane) = pk;
      else         *(unsigned int*)(Ubuf + ub + t*32 + (lane-32)) = pk;
    }
    if (t<63){
      const int g0 = (t>>4)<<2;      // tile-aligned start: all reads valid/finite
      #pragma unroll
      for (int g=g0; g<16; ++g){
        float4 av = *(const float4*)&Abt[t][g*4];
        racc[g*4+0] -= av.x*w;       // updates at idx<=t hit dead accumulators
        racc[g*4+1] -= av.y*w;
        racc[g*4+2] -= av.z*w;
        racc[g*4+3] -= av.w*w;
      }
    }
  }
}

// ---- phase B: one wave per (b,h), serial over 64 chunks.
// PREC=1: Sent stored f32; always: S and E applied as bf16 hi+lo pairs.
template<int PREC>
__global__ __launch_bounds__(64) void k_pB(const unsigned short* __restrict__ kbuf,
                                           unsigned short* webuf,
                                           const unsigned short* __restrict__ Ubuf,
                                           void* __restrict__ SentP){
  __shared__ float Sl[32][33];
  __shared__ unsigned short El[64][40];
  __shared__ unsigned short Ell[64][40];
  __shared__ unsigned short Kl[64][40];
  const int bh = blockIdx.x, b = bh>>2, h = bh&3;
  const int lane = threadIdx.x, fr = lane&15, fg = lane>>4;
  for (int i=lane; i<32*33; i+=64) ((float*)Sl)[i] = 0.f;
  f32x4 sc[2][2];
  #pragma unroll
  for (int it=0;it<2;it++){
    #pragma unroll
    for (int ct=0;ct<2;ct++) sc[it][ct]=(f32x4){0.f,0.f,0.f,0.f};
  }

  for (int c=0;c<NC;c++){
    const size_t base = ((size_t)b*TT + c*64)*128 + h*32;
    const size_t ub = ((size_t)bh*NC + c)*2048;
    {
      const unsigned short* kr = kbuf + base + (size_t)lane*128;
      const unsigned short* wr = webuf + base + (size_t)lane*128;
      uint4 a0=*(const uint4*)(kr),   a1=*(const uint4*)(kr+8);
      uint4 a2=*(const uint4*)(kr+16),a3=*(const uint4*)(kr+24);
      uint4 b0=*(const uint4*)(wr),   b1=*(const uint4*)(wr+8);
      uint4 b2=*(const uint4*)(wr+16),b3=*(const uint4*)(wr+24);
      *(uint4*)&Kl[lane][0]=a0; *(uint4*)&Kl[lane][8]=a1;
      *(uint4*)&Kl[lane][16]=a2; *(uint4*)&Kl[lane][24]=a3;
      *(uint4*)&El[lane][0]=b0; *(uint4*)&El[lane][8]=b1;
      *(uint4*)&El[lane][16]=b2; *(uint4*)&El[lane][24]=b3;
    }
    short8 uf[4];
    #pragma unroll
    for (int mt=0;mt<4;mt++)
      uf[mt] = *(const short8*)(Ubuf + ub + (size_t)(mt*16+fr)*32 + fg*8);
    // acc init = W
    f32x4 acc[4][2];
    #pragma unroll
    for (int mt=0;mt<4;mt++){
      #pragma unroll
      for (int ct=0;ct<2;ct++){
        #pragma unroll
        for (int r=0;r<4;r++)
          acc[mt][ct][r] = b2f(El[mt*16+fg*4+r][ct*16+fr]);
      }
    }
    // S B-frags as hi+lo of (-S); store S_entry (f32 if PREC)
    short8 sb[2], sbl[2];
    #pragma unroll
    for (int ct=0;ct<2;ct++){
      short8 neg, negl;
      float pos[8];
      #pragma unroll
      for (int jj=0;jj<8;jj++){
        float sv = Sl[fg*8+jj][ct*16+fr];
        pos[jj] = sv;
        float nv = -sv;
        unsigned short hi = f2b(nv);
        neg[jj]=(short)hi;
        negl[jj]=(short)f2b(nv - b2f(hi));
      }
      sb[ct]=neg; sbl[ct]=negl;
      if (PREC){
        float* Sf = (float*)SentP + ((size_t)bh*NC + c)*1024 + ct*512 + lane*8;
        *(float4*)Sf     = (float4){pos[0],pos[1],pos[2],pos[3]};
        *(float4*)(Sf+4) = (float4){pos[4],pos[5],pos[6],pos[7]};
      } else {
        short8 p8;
        #pragma unroll
        for (int jj=0;jj<8;jj++) p8[jj]=(short)f2b(pos[jj]);
        *(short8*)((unsigned short*)SentP + ((size_t)bh*NC + c)*1024 + ct*512 + lane*8) = p8;
      }
    }
    // E = W + U*(-S_hi) + U*(-S_lo)
    #pragma unroll
    for (int mt=0;mt<4;mt++){
      #pragma unroll
      for (int ct=0;ct<2;ct++){
        acc[mt][ct] = __builtin_amdgcn_mfma_f32_16x16x32_bf16(uf[mt], sb[ct],  acc[mt][ct],0,0,0);
        acc[mt][ct] = __builtin_amdgcn_mfma_f32_16x16x32_bf16(uf[mt], sbl[ct], acc[mt][ct],0,0,0);
      }
    }
    // write E hi (LDS+global) and E lo (LDS)
    #pragma unroll
    for (int mt=0;mt<4;mt++){
      #pragma unroll
      for (int ct=0;ct<2;ct++){
        #pragma unroll
        for (int r=0;r<4;r++){
          float ef = acc[mt][ct][r];
          unsigned short eh = f2b(ef);
          int t = mt*16+fg*4+r, j = ct*16+fr;
          El[t][j] = eh;
          Ell[t][j] = f2b(ef - b2f(eh));
          webuf[base + (size_t)t*128 + j] = eh;
        }
      }
    }
    // S += K^T (E_hi + E_lo)
    short8 ka[2][2], eb[2][2], ebl[2][2];
    #pragma unroll
    for (int it=0;it<2;it++){
      #pragma unroll
      for (int ks=0;ks<2;ks++){
        short8 tmp;
        #pragma unroll
        for (int jj=0;jj<8;jj++) tmp[jj] = (short)Kl[ks*32+fg*8+jj][it*16+fr];
        ka[it][ks]=tmp;
      }
    }
    #pragma unroll
    for (int ct=0;ct<2;ct++){
      #pragma unroll
      for (int ks=0;ks<2;ks++){
        short8 t1v, t2v;
        #pragma unroll
        for (int jj=0;jj<8;jj++){
          t1v[jj] = (short)El[ks*32+fg*8+jj][ct*16+fr];
          t2v[jj] = (short)Ell[ks*32+fg*8+jj][ct*16+fr];
        }
        eb[ct][ks]=t1v; ebl[ct][ks]=t2v;
      }
    }
    #pragma unroll
    for (int it=0;it<2;it++){
      #pragma unroll
      for (int ct=0;ct<2;ct++){
        #pragma unroll
        for (int ks=0;ks<2;ks++){
          sc[it][ct] = __builtin_amdgcn_mfma_f32_16x16x32_bf16(ka[it][ks], eb[ct][ks],  sc[it][ct],0,0,0);
          sc[it][ct] = __builtin_amdgcn_mfma_f32_16x16x32_bf16(ka[it][ks], ebl[ct][ks], sc[it][ct],0,0,0);
        }
      }
    }
    // master S (f32) back to Sl
    #pragma unroll
    for (int it=0;it<2;it++){
      #pragma unroll
      for (int ct=0;ct<2;ct++){
        #pragma unroll
        for (int r=0;r<4;r++)
          Sl[it*16+fg*4+r][ct*16+fr] = sc[it][ct][r];
      }
    }
  }
}

// ---- phase C: O = Q S_entry + tril(QK^T) E ; P applied as bf16 hi+lo ----
template<int PREC>
__global__ __launch_bounds__(64) void k_pC(unsigned short* qobuf,
                                           const unsigned short* __restrict__ kbuf,
                                           const unsigned short* __restrict__ ebuf,
                                           const void* __restrict__ SentP){
  __shared__ unsigned short Pl[64][72];
  __shared__ unsigned short Plo[64][72];
  __shared__ unsigned short El[64][40];
  const int c = blockIdx.x, bh = blockIdx.y, b=bh>>2, h=bh&3;
  const int lane=threadIdx.x, fr=lane&15, fg=lane>>4;
  const size_t base = ((size_t)b*TT + c*64)*128 + h*32;
  #pragma unroll
  for (int i=0;i<9;i++){
    *(uint4*)&Pl[lane][i*8]  = (uint4){0u,0u,0u,0u};
    *(uint4*)&Plo[lane][i*8] = (uint4){0u,0u,0u,0u};
  }
  {
    const unsigned short* er = ebuf + base + (size_t)lane*128;
    uint4 a0=*(const uint4*)(er),   a1=*(const uint4*)(er+8);
    uint4 a2=*(const uint4*)(er+16),a3=*(const uint4*)(er+24);
    *(uint4*)&El[lane][0]=a0; *(uint4*)&El[lane][8]=a1;
    *(uint4*)&El[lane][16]=a2; *(uint4*)&El[lane][24]=a3;
  }
  short8 qf[4], kf[4];
  #pragma unroll
  for (int mt=0;mt<4;mt++){
    qf[mt] = *(const short8*)(qobuf + base + (size_t)(mt*16+fr)*128 + fg*8);
    kf[mt] = *(const short8*)(kbuf  + base + (size_t)(mt*16+fr)*128 + fg*8);
  }
  // P = tril(QK^T) -> hi/lo
  #pragma unroll
  for (int mt=0;mt<4;mt++){
    #pragma unroll
    for (int nt=0;nt<4;nt++){
      if (nt>mt) continue;
      f32x4 p = (f32x4){0.f,0.f,0.f,0.f};
      p = __builtin_amdgcn_mfma_f32_16x16x32_bf16(qf[mt], kf[nt], p,0,0,0);
      #pragma unroll
      for (int r=0;r<4;r++){
        int t = mt*16+fg*4+r, s = nt*16+fr;
        float pv = p[r];
        unsigned short ph = f2b(pv);
        Pl[t][s]  = (s<=t)? ph : (unsigned short)0;
        Plo[t][s] = (s<=t)? f2b(pv - b2f(ph)) : (unsigned short)0;
      }
    }
  }
  // O = Q*S_entry
  f32x4 acc[4][2];
  #pragma unroll
  for (int mt=0;mt<4;mt++){
    #pragma unroll
    for (int ct=0;ct<2;ct++) acc[mt][ct]=(f32x4){0.f,0.f,0.f,0.f};
  }
  if (PREC){
    short8 sfh[2], sfl[2];
    #pragma unroll
    for (int ct=0;ct<2;ct++){
      const float* Sf = (const float*)SentP + ((size_t)bh*NC + c)*1024 + ct*512 + lane*8;
      float4 v0 = *(const float4*)Sf;
      float4 v1 = *(const float4*)(Sf+4);
      float sv[8] = {v0.x,v0.y,v0.z,v0.w,v1.x,v1.y,v1.z,v1.w};
      short8 hh, ll;
      #pragma unroll
      for (int jj=0;jj<8;jj++){
        unsigned short hi = f2b(sv[jj]);
        hh[jj]=(short)hi; ll[jj]=(short)f2b(sv[jj]-b2f(hi));
      }
      sfh[ct]=hh; sfl[ct]=ll;
    }
    #pragma unroll
    for (int mt=0;mt<4;mt++){
      #pragma unroll
      for (int ct=0;ct<2;ct++){
        acc[mt][ct]=__builtin_amdgcn_mfma_f32_16x16x32_bf16(qf[mt], sfh[ct], acc[mt][ct],0,0,0);
        acc[mt][ct]=__builtin_amdgcn_mfma_f32_16x16x32_bf16(qf[mt], sfl[ct], acc[mt][ct],0,0,0);
      }
    }
  } else {
    short8 sf[2];
    #pragma unroll
    for (int ct=0;ct<2;ct++)
      sf[ct] = *(const short8*)((const unsigned short*)SentP + ((size_t)bh*NC + c)*1024 + ct*512 + lane*8);
    #pragma unroll
    for (int mt=0;mt<4;mt++){
      #pragma unroll
      for (int ct=0;ct<2;ct++)
        acc[mt][ct]=__builtin_amdgcn_mfma_f32_16x16x32_bf16(qf[mt], sf[ct], acc[mt][ct],0,0,0);
    }
  }
  // O += (P_hi + P_lo)*E
  short8 ebf[2][2];
  #pragma unroll
  for (int ct=0;ct<2;ct++){
    #pragma unroll
    for (int ks=0;ks<2;ks++){
      short8 tmp;
      #pragma unroll
      for (int jj=0;jj<8;jj++) tmp[jj]=(short)El[ks*32+fg*8+jj][ct*16+fr];
      ebf[ct][ks]=tmp;
    }
  }
  #pragma unroll
  for (int mt=0;mt<4;mt++){
    #pragma unroll
    for (int ks=0;ks<2;ks++){
      short8 pa  = *(const short8*)&Pl[mt*16+fr][ks*32+fg*8];
      short8 pal = *(const short8*)&Plo[mt*16+fr][ks*32+fg*8];
      #pragma unroll
      for (int ct=0;ct<2;ct++){
        acc[mt][ct]=__builtin_amdgcn_mfma_f32_16x16x32_bf16(pa,  ebf[ct][ks], acc[mt][ct],0,0,0);
        acc[mt][ct]=__builtin_amdgcn_mfma_f32_16x16x32_bf16(pal, ebf[ct][ks], acc[mt][ct],0,0,0);
      }
    }
  }
  // store O over Q
  #pragma unroll
  for (int mt=0;mt<4;mt++){
    #pragma unroll
    for (int ct=0;ct<2;ct++){
      #pragma unroll
      for (int r=0;r<4;r++)
        qobuf[base + (size_t)(mt*16+fg*4+r)*128 + ct*16+fr] = f2b(acc[mt][ct][r]);
    }
  }
}

// ---------------- fallback sequential scan ----------------
__global__ __launch_bounds__(64) void k_scan(const unsigned short* q, const unsigned short* k,
                                             const unsigned short* v, const float* beta,
                                             unsigned short* o){
  int b = blockIdx.x>>2, hh = blockIdx.x&3;
  int lane = threadIdx.x;
  int j = lane&31, ih = lane>>5;
  float S[16];
  #pragma unroll
  for (int m=0;m<16;m++) S[m]=0.f;
  size_t idx0 = ((size_t)b*TT*HH + hh)*dh;
  size_t bidx0 = (size_t)b*TT*HH + hh;
  const unsigned short* kp = k + idx0 + ih*16;
  const unsigned short* qp = q + idx0 + ih*16;
  for (int t=0;t<TT;t++){
    size_t ofs=(size_t)t*128;
    uint4 ka=*(const uint4*)(kp+ofs), kb=*(const uint4*)(kp+ofs+8);
    uint4 qa=*(const uint4*)(qp+ofs), qb=*(const uint4*)(qp+ofs+8);
    float kf[16], qf[16];
    kf[0]=blo(ka.x);kf[1]=bhi(ka.x);kf[2]=blo(ka.y);kf[3]=bhi(ka.y);
    kf[4]=blo(ka.z);kf[5]=bhi(ka.z);kf[6]=blo(ka.w);kf[7]=bhi(ka.w);
    kf[8]=blo(kb.x);kf[9]=bhi(kb.x);kf[10]=blo(kb.y);kf[11]=bhi(kb.y);
    kf[12]=blo(kb.z);kf[13]=bhi(kb.z);kf[14]=blo(kb.w);kf[15]=bhi(kb.w);
    qf[0]=blo(qa.x);qf[1]=bhi(qa.x);qf[2]=blo(qa.y);qf[3]=bhi(qa.y);
    qf[4]=blo(qa.z);qf[5]=bhi(qa.z);qf[6]=blo(qa.w);qf[7]=bhi(qa.w);
    qf[8]=blo(qb.x);qf[9]=bhi(qb.x);qf[10]=blo(qb.y);qf[11]=bhi(qb.y);
    qf[12]=blo(qb.z);qf[13]=bhi(qb.z);qf[14]=blo(qb.w);qf[15]=bhi(qb.w);
    float vc = b2f(v[idx0+ofs+j]), bc = beta[bidx0+(size_t)t*4];
    float p0=0,p1=0,p2=0,p3=0;
    #pragma unroll
    for (int m=0;m<4;m++){
      p0 += S[m]*kf[m]; p1 += S[m+4]*kf[m+4]; p2 += S[m+8]*kf[m+8]; p3 += S[m+12]*kf[m+12];
    }
    float p = (p0+p1)+(p2+p3);
    p += __shfl_xor(p, 32, 64);
    float err = (vc - p)*bc;
    float o0=0,o1=0,o2=0,o3=0;
    #pragma unroll
    for (int m=0;m<4;m++){
      S[m]    += kf[m]*err;     o0 += S[m]*qf[m];
      S[m+4]  += kf[m+4]*err;   o1 += S[m+4]*qf[m+4];
      S[m+8]  += kf[m+8]*err;   o2 += S[m+8]*qf[m+8];
      S[m+12] += kf[m+12]*err;  o3 += S[m+12]*qf[m+12];
    }
    float oo = (o0+o1)+(o2+o3);
    oo += __shfl_xor(oo, 32, 64);
    if (ih==0) o[idx0 + ofs + j] = f2b(oo);
  }
}

// ---------------- o = rms(o, hnw)*silu(gate) ----------------
__global__ __launch_bounds__(256) void k_ogate(const unsigned short* __restrict__ o, const unsigned short* __restrict__ gate,
                                               const float* __restrict__ hnwl, unsigned short* __restrict__ tmp){
  int tid=threadIdx.x;
  size_t bt = (size_t)blockIdx.x*2 + (tid>>7);
  int c = tid&127;
  size_t i = bt*DD + c;
  float ov = b2f(o[i]);
  float ss = ov*ov;
  #pragma unroll
  for (int m=1;m<32;m<<=1) ss += __shfl_xor(ss,m,64);
  float r = rsqrtf(ss*(1.0f/32.0f)+1e-5f);
  float g = b2f(gate[i]);
  tmp[i] = f2b(ov*r*hnwl[c&31]*siluf(g));
}

// ---------------- final head ----------------
__global__ __launch_bounds__(256) void k_head(const unsigned short* __restrict__ hf, const float* __restrict__ hw,
                                              float* __restrict__ out){
  int gid = blockIdx.x*256+threadIdx.x;
  if (gid >= MM*VV) return;
  int row = gid/VV, n = gid - row*VV;
  const unsigned short* a = hf + (size_t)row*DD;
  const float* w = hw + n*DD;
  float s=0.f;
  #pragma unroll
  for (int k2=0;k2<128;k2+=8){
    uint4 av = *(const uint4*)(a+k2);
    float4 wa = *(const float4*)(w+k2);
    float4 wb = *(const float4*)(w+k2+4);
    s += blo(av.x)*wa.x + bhi(av.x)*wa.y + blo(av.y)*wa.z + bhi(av.y)*wa.w;
    s += blo(av.z)*wb.x + bhi(av.z)*wb.y + blo(av.w)*wb.z + bhi(av.w)*wb.w;
  }
  out[gid] = s;
}

extern "C" void kernel_launch(void* const* d_in, const int* in_sizes, int n_in,
                              void* d_out, int out_size, void* d_ws, size_t ws_size,
                              hipStream_t stream){
  const int*   x   = (const int*)d_in[0];
  const float* emb = (const float*)d_in[1];
  const float* qw  = (const float*)d_in[2];
  const float* kw  = (const float*)d_in[3];
  const float* vw  = (const float*)d_in[4];
  const float* qcw = (const float*)d_in[5];
  const float* qcb = (const float*)d_in[6];
  const float* kcw = (const float*)d_in[7];
  const float* kcb = (const float*)d_in[8];
  const float* vcw = (const float*)d_in[9];
  const float* vcb = (const float*)d_in[10];
  const float* ow  = (const float*)d_in[11];
  const float* gw  = (const float*)d_in[12];
  const float* bw  = (const float*)d_in[13];
  const float* hnw = (const float*)d_in[14];
  const float* n1w = (const float*)d_in[15];
  const float* n2w = (const float*)d_in[16];
  const float* m1w = (const float*)d_in[17];
  const float* m2w = (const float*)d_in[18];
  const float* fnw = (const float*)d_in[19];
  const float* hw  = (const float*)d_in[20];

  // ws layout: h | hn | A | B | C | beta | halo | U | Sent(f32 or bf16)
  char* ws = (char*)d_ws;
  size_t off = 0;
  float* h             = (float*)(ws+off);          off += (size_t)MM*DD*4;
  unsigned short* hn   = (unsigned short*)(ws+off); off += (size_t)MM*DD*2;
  unsigned short* A    = (unsigned short*)(ws+off); off += (size_t)MM*DD*2;
  unsigned short* B    = (unsigned short*)(ws+off); off += (size_t)MM*DD*2;
  unsigned short* C    = (unsigned short*)(ws+off); off += (size_t)MM*DD*2;
  float* beta          = (float*)(ws+off);          off += (size_t)MM*HH*4;
  unsigned short* halo = (unsigned short*)(ws+off); off += (size_t)NCHUNK*9*128*2;
  unsigned short* U    = (unsigned short*)(ws+off); off += (size_t)MM*DD*2;      // 8192 chunks * 2048
  void* SentP          = (void*)(ws+off);
  const size_t NEED1 = off + (size_t)8192*1024*4;   // f32 Sent
  const size_t NEED0 = off + (size_t)8192*1024*2;   // bf16 Sent
  unsigned short* t1   = A;
  const int mode = (ws_size >= NEED1) ? 1 : (ws_size >= NEED0) ? 0 : -1;

  k_embed<<<MM*DD/256, 256, 0, stream>>>(x, emb, h);
  for (int l=0;l<LL;l++){
    k_rms<<<MM/4,256,0,stream>>>(h, n1w + l*DD, hn);
    k_gemm<0,0><<<dim3(MM/128,2),256,0,stream>>>(hn, qw + l*DD*DD, A, 128, 128);
    k_gemm<0,0><<<dim3(MM/128,2),256,0,stream>>>(hn, kw + l*DD*DD, B, 128, 128);
    k_gemm<0,0><<<dim3(MM/128,2),256,0,stream>>>(hn, vw + l*DD*DD, C, 128, 128);
    k_beta<<<MM/64,256,0,stream>>>(hn, bw + l*HH*DD, beta);
    k_halo<<<NCHUNK*9*128/256,256,0,stream>>>(A, B, C, halo);
    k_conv_ip<<<dim3(NCHUNK,3),256,0,stream>>>(A, B, C,
                                  qcw+l*DD*4, qcb+l*DD, kcw+l*DD*4, kcb+l*DD, vcw+l*DD*4, vcb+l*DD,
                                  halo);
    if (mode >= 0){
      k_pA<<<dim3(NC, BB*HH), 64, 0, stream>>>(B, C, beta, U);
      if (mode==1){
        k_pB<1><<<BB*HH, 64, 0, stream>>>(B, C, U, SentP);
        k_pC<1><<<dim3(NC, BB*HH), 64, 0, stream>>>(A, B, C, SentP);
      } else {
        k_pB<0><<<BB*HH, 64, 0, stream>>>(B, C, U, SentP);
        k_pC<0><<<dim3(NC, BB*HH), 64, 0, stream>>>(A, B, C, SentP);
      }
    } else {
      k_scan<<<BB*HH,64,0,stream>>>(A, B, C, beta, A);
    }
    k_gemm<0,0><<<dim3(MM/128,2),256,0,stream>>>(hn, gw + l*DD*DD, C, 128, 128);
    k_ogate<<<MM/2,256,0,stream>>>(A, C, hnw+l*dh, B);
    k_gemm<0,1><<<dim3(MM/128,2),256,0,stream>>>(B, ow + l*DD*DD, h, 128, 128);
    k_rms<<<MM/4,256,0,stream>>>(h, n2w + l*DD, hn);
    k_gemm<1,0><<<dim3(MM/128,4),256,0,stream>>>(hn, m1w + l*2*DD*DD, t1, 256, 128);
    k_gemm<0,1><<<dim3(MM/128,2),256,0,stream>>>(t1, m2w + l*2*DD*DD, h, 128, 256);
  }
  k_rms<<<MM/4,256,0,stream>>>(h, fnw, hn);
  k_head<<<(MM*VV+255)/256,256,0,stream>>>(hn, hw, (float*)d_out);
}

// Round 8
// 3297.014 us; speedup vs baseline: 2.2150x; 2.2150x over previous
//
#include <hip/hip_runtime.h>
#include <hip/hip_bf16.h>
#include <math.h>

#define BB 32
#define TT 4096
#define DD 128
#define HH 4
#define dh 32
#define VV 33
#define LL 4
#define MM (BB*TT)   // 131072 rows
#define NCHUNK (MM/128)  // 1024
#define NC 64        // delta chunks per (b,h): TT/64

typedef short short8 __attribute__((ext_vector_type(8)));
typedef float f32x4 __attribute__((ext_vector_type(4)));

__device__ __forceinline__ float b2f(unsigned short u){
  union{float f; unsigned int x;} v; v.x = ((unsigned int)u)<<16; return v.f;
}
__device__ __forceinline__ unsigned short f2b(float f){
  union{float f; unsigned int x;} v; v.f=f;
  unsigned int r = v.x + 0x7fffu + ((v.x>>16)&1u);
  return (unsigned short)(r>>16);
}
__device__ __forceinline__ float blo(unsigned int u){ union{float f;unsigned int x;}v; v.x=u<<16; return v.f;}
__device__ __forceinline__ float bhi(unsigned int u){ union{float f;unsigned int x;}v; v.x=u&0xffff0000u; return v.f;}
__device__ __forceinline__ float siluf(float x){ return x/(1.0f+expf(-x)); }

// ---------------- embedding ----------------
__global__ __launch_bounds__(256) void k_embed(const int* __restrict__ x, const float* __restrict__ emb,
                                               float* __restrict__ h){
  int i = blockIdx.x*256 + threadIdx.x;
  int bt = i>>7, c = i&127;
  h[i] = emb[x[bt]*DD + c];
}

// ---------------- rms norm ----------------
__global__ __launch_bounds__(256) void k_rms(const float* __restrict__ src, const float* __restrict__ w,
                                             unsigned short* __restrict__ dst){
  int row = blockIdx.x*4 + (threadIdx.x>>6);
  int lane = threadIdx.x&63;
  const float2 xv = *(const float2*)(src + (size_t)row*DD + lane*2);
  float ss = xv.x*xv.x + xv.y*xv.y;
  #pragma unroll
  for (int m=1;m<64;m<<=1) ss += __shfl_xor(ss,m,64);
  float sc = rsqrtf(ss*(1.0f/128.0f)+1e-5f);
  const float2 wv = *(const float2*)(w + lane*2);
  unsigned int o = ((unsigned int)f2b(xv.y*sc*wv.y)<<16) | (unsigned int)f2b(xv.x*sc*wv.x);
  *(unsigned int*)(dst + (size_t)row*DD + lane*2) = o;
}

// ---------------- MFMA GEMM: out[M,N] = A[M,K] @ W[N,K]^T ----------------
template<int ACT, int OUTADD>
__global__ __launch_bounds__(256) void k_gemm(const unsigned short* __restrict__ A,
                                              const float* __restrict__ W,
                                              void* __restrict__ outp, int N, int K){
  __shared__ __align__(16) unsigned short As[128*128];
  __shared__ __align__(16) unsigned short Ws[64*128];
  const int tid = threadIdx.x;
  const int lane = tid & 63, wave = tid >> 6;
  const int row0 = blockIdx.x*128, col0 = blockIdx.y*64;
  const int wr0 = (wave&1)*64, wc0 = (wave>>1)*32;
  const int fr = lane & 15, fq = lane >> 4;
  f32x4 acc[4][2];
  #pragma unroll
  for (int m=0;m<4;m++){
    #pragma unroll
    for (int n=0;n<2;n++) acc[m][n] = (f32x4){0.f,0.f,0.f,0.f};
  }

  for (int kc=0; kc<K; kc+=128){
    #pragma unroll
    for (int ii=0; ii<8; ++ii){
      int flat = tid + ii*256;
      int r = flat>>4, g = flat&15;
      uint4 gv = *(const uint4*)(A + (size_t)(row0+r)*K + kc + g*8);
      *(uint4*)&As[r*128 + ((g^(r&7))<<3)] = gv;
    }
    #pragma unroll
    for (int ii=0; ii<8; ++ii){
      int flat = tid + ii*256;
      int n = flat>>5, q4 = flat&31;
      float4 wv = *(const float4*)(W + (size_t)(col0+n)*K + kc + q4*4);
      uint2 pk;
      pk.x = (unsigned int)f2b(wv.x) | ((unsigned int)f2b(wv.y)<<16);
      pk.y = (unsigned int)f2b(wv.z) | ((unsigned int)f2b(wv.w)<<16);
      int dst = n*128 + ((((q4>>1)^(n&7))<<3) | ((q4&1)<<2));
      *(uint2*)&Ws[dst] = pk;
    }
    __syncthreads();
    #pragma unroll
    for (int ks=0; ks<4; ++ks){
      int gg = ks*4 + fq;
      short8 a[4], b[2];
      #pragma unroll
      for (int m=0;m<4;m++){
        int row = wr0 + m*16 + fr;
        a[m] = *(const short8*)&As[row*128 + ((gg^(row&7))<<3)];
      }
      #pragma unroll
      for (int n=0;n<2;n++){
        int col = wc0 + n*16 + fr;
        b[n] = *(const short8*)&Ws[col*128 + ((gg^(col&7))<<3)];
      }
      #pragma unroll
      for (int m=0;m<4;m++){
        #pragma unroll
        for (int n=0;n<2;n++)
          acc[m][n] = __builtin_amdgcn_mfma_f32_16x16x32_bf16(a[m], b[n], acc[m][n], 0, 0, 0);
      }
    }
    __syncthreads();
  }

  if (OUTADD){
    float* O = (float*)outp;
    #pragma unroll
    for (int m=0;m<4;m++){
      #pragma unroll
      for (int n=0;n<2;n++){
        int ccol = col0 + wc0 + n*16 + fr;
        #pragma unroll
        for (int r=0;r<4;r++){
          int rrow = row0 + wr0 + m*16 + fq*4 + r;
          O[(size_t)rrow*N + ccol] += acc[m][n][r];
        }
      }
    }
  } else {
    unsigned short* O = (unsigned short*)outp;
    #pragma unroll
    for (int m=0;m<4;m++){
      #pragma unroll
      for (int n=0;n<2;n++){
        int ccol = col0 + wc0 + n*16 + fr;
        #pragma unroll
        for (int r=0;r<4;r++){
          int rrow = row0 + wr0 + m*16 + fq*4 + r;
          float vv = acc[m][n][r];
          if (ACT) vv = siluf(vv);
          O[(size_t)rrow*N + ccol] = f2b(vv);
        }
      }
    }
  }
}

// ---------------- beta = sigmoid(hn @ bw^T), N=4 ----------------
__global__ __launch_bounds__(256) void k_beta(const unsigned short* __restrict__ hn,
                                              const float* __restrict__ bwl, float* __restrict__ beta){
  __shared__ unsigned short As[64*128];
  int tid = threadIdx.x; int row0 = blockIdx.x*64;
  #pragma unroll
  for (int ii=0;ii<4;ii++){
    int flat = tid + ii*256;
    int r = flat>>4, v16 = flat&15;
    *(uint4*)&As[r*128 + v16*8] = *(const uint4*)(hn + (size_t)(row0+r)*DD + v16*8);
  }
  __syncthreads();
  int r = tid>>2, n = tid&3;
  const float* wr = bwl + n*DD;
  const unsigned short* ar = &As[r*128];
  float s = 0.f;
  #pragma unroll
  for (int k=0;k<128;k+=8){
    uint4 a = *(const uint4*)(ar + k);
    float4 wa = *(const float4*)(wr + k);
    float4 wb = *(const float4*)(wr + k + 4);
    s += blo(a.x)*wa.x + bhi(a.x)*wa.y + blo(a.y)*wa.z + bhi(a.y)*wa.w;
    s += blo(a.z)*wb.x + bhi(a.z)*wb.y + blo(a.w)*wb.z + bhi(a.w)*wb.w;
  }
  beta[(size_t)(row0+r)*HH + n] = 1.0f/(1.0f+expf(-s));
}

// ---------------- halo save ----------------
__global__ __launch_bounds__(256) void k_halo(const unsigned short* __restrict__ A,
                                              const unsigned short* __restrict__ B,
                                              const unsigned short* __restrict__ C,
                                              unsigned short* __restrict__ halo){
  int i = blockIdx.x*256 + threadIdx.x;
  int ch = i & 127;
  int rt = i >> 7;
  int r3 = rt % 3;
  int tn = (rt/3) % 3;
  int ck = rt / 9;
  unsigned short v = 0;
  if ((ck & 31) != 0){
    const unsigned short* X = (tn==0) ? A : (tn==1) ? B : C;
    v = X[((size_t)ck*128 - 3 + r3)*DD + ch];
  }
  halo[(size_t)i] = v;
}

// ---------------- in-place causal conv(4)+silu(+l2n) ----------------
__global__ __launch_bounds__(256) void k_conv_ip(
    unsigned short* __restrict__ A, unsigned short* __restrict__ B, unsigned short* __restrict__ C,
    const float* __restrict__ qcw, const float* __restrict__ qcb,
    const float* __restrict__ kcw, const float* __restrict__ kcb,
    const float* __restrict__ vcw, const float* __restrict__ vcb,
    const unsigned short* __restrict__ halo){
  __shared__ __align__(16) unsigned short Xs[131*128];
  const int tid = threadIdx.x;
  const int ck = blockIdx.x, tn = blockIdx.y;
  unsigned short* X = (tn==0) ? A : (tn==1) ? B : C;
  const float* w = (tn==0) ? qcw : (tn==1) ? kcw : vcw;
  const float* bi = (tn==0) ? qcb : (tn==1) ? kcb : vcb;

  if (tid < 48){
    int lr = tid>>4, c16 = tid&15;
    *(uint4*)&Xs[lr*128 + c16*8] = *(const uint4*)&halo[((size_t)(ck*3+tn)*3 + lr)*128 + c16*8];
  }
  #pragma unroll
  for (int ii=0; ii<8; ++ii){
    int flat = tid + ii*256;
    int r = flat>>4, c16 = flat&15;
    *(uint4*)&Xs[(3+r)*128 + c16*8] = *(const uint4*)&X[((size_t)ck*128 + r)*DD + c16*8];
  }
  __syncthreads();

  const int rh = tid>>7, c = tid&127;
  float w0=w[c*4+0], w1=w[c*4+1], w2=w[c*4+2], w3=w[c*4+3];
  float bc = bi[c];
  #pragma unroll 2
  for (int rr=0; rr<64; ++rr){
    int row = rr*2 + rh;
    float y = bc + w0*b2f(Xs[(row+0)*128+c]) + w1*b2f(Xs[(row+1)*128+c])
                 + w2*b2f(Xs[(row+2)*128+c]) + w3*b2f(Xs[(row+3)*128+c]);
    y = siluf(y);
    if (tn < 2){
      float s = y*y;
      #pragma unroll
      for (int m=1;m<32;m<<=1) s += __shfl_xor(s,m,64);
      y *= rsqrtf(s + 1e-6f);
      if (tn==0) y *= 0.17677669529663687f;
    }
    X[((size_t)ck*128 + row)*DD + c] = f2b(y);
  }
}

// ======================= chunked delta-rule (WY form) =======================
// chunk C=64, per (b,h): M = I + stril(diag(beta) K K^T, -1)
// W = M^-1 B V, U = M^-1 B K  (phase A, parallel over 8192 chunks)
// E_c = W_c - U_c S ; S += K_c^T E_c  (phase B, serial over 64 chunks, 128 blocks)
// O = Q S_entry + tril(Q K^T, incl diag) E   (phase C, parallel)
// v-layout: elem(b,t,h,d) = (b*TT+t)*128 + h*32 + d

// ---- phase A (v3): 4-wave cooperative blocked forward substitution ----
// 256 threads. Wave p owns row-tile p (16 rows); lane owns one column
// (lane<32: V/W col, lane>=32: K/U col). racc[16] per lane -> no spills.
// Abt[s][t] = beta_t*(k_t.k_s); every Abt entry a wave reads was written by
// itself (wave q builds A[tile q][tiles<=q]) -> no barrier needed for Abt.
__global__ __launch_bounds__(256) void k_pA(const unsigned short* __restrict__ kbuf,
                                            unsigned short* vwbuf,
                                            const float* __restrict__ betab,
                                            unsigned short* __restrict__ Ubuf){
  __shared__ float Abt[64][68];   // [s][t]
  __shared__ float sol[64][72];   // [t][col]  col<32: W, col>=32: U
  __shared__ float bs[64];
  const int c = blockIdx.x, bh = blockIdx.y;
  const int b = bh>>2, h = bh&3;
  const int tid = threadIdx.x;
  const int wave = tid>>6, lane = tid&63;
  const int fr = lane&15, fg = lane>>4;
  const size_t base = ((size_t)b*TT + c*64)*128 + h*32;
  const size_t bbase = ((size_t)b*TT + c*64)*4 + h;
  const size_t ub = ((size_t)bh*NC + c)*2048;

  if (tid < 64) bs[tid] = betab[bbase + (size_t)tid*4];

  short8 kA  = *(const short8*)(kbuf + base + (size_t)(wave*16+fr)*128 + fg*8);
  short8 kB0 = *(const short8*)(kbuf + base + (size_t)( 0+fr)*128 + fg*8);
  short8 kB1 = *(const short8*)(kbuf + base + (size_t)(16+fr)*128 + fg*8);
  short8 kB2 = *(const short8*)(kbuf + base + (size_t)(32+fr)*128 + fg*8);
  short8 kB3 = *(const short8*)(kbuf + base + (size_t)(48+fr)*128 + fg*8);
  __syncthreads();   // bs visible to all waves

  {
    float4 bsv = *(const float4*)&bs[wave*16 + fg*4];
    f32x4 a;
    // wave builds A rows of its tile vs col-tiles nt<=wave (diag tile's upper
    // half is garbage-but-finite; never read)
    #define BUILD(nt, kB) if (wave >= nt){ \
      a = (f32x4){0.f,0.f,0.f,0.f}; \
      a = __builtin_amdgcn_mfma_f32_16x16x32_bf16(kA, kB, a, 0,0,0); \
      Abt[nt*16+fr][wave*16+fg*4+0] = a[0]*bsv.x; \
      Abt[nt*16+fr][wave*16+fg*4+1] = a[1]*bsv.y; \
      Abt[nt*16+fr][wave*16+fg*4+2] = a[2]*bsv.z; \
      Abt[nt*16+fr][wave*16+fg*4+3] = a[3]*bsv.w; }
    BUILD(0, kB0) BUILD(1, kB1) BUILD(2, kB2) BUILD(3, kB3)
    #undef BUILD
  }

  // init racc = x * beta for this wave's 16 rows (own column)
  const unsigned short* xp = ((lane<32)? (const unsigned short*)vwbuf : kbuf) + base + (lane&31);
  float racc[16];
  #pragma unroll
  for (int r=0;r<16;r++)
    racc[r] = b2f(xp[(size_t)(wave*16+r)*128]) * bs[wave*16+r];

  // blocked sweep
  #pragma unroll
  for (int p=0;p<4;p++){
    if (wave == p){
      #pragma unroll
      for (int r=0;r<16;r++){
        float w_ = racc[r];
        sol[p*16+r][lane] = w_;
        #pragma unroll
        for (int r2=r+1;r2<16;r2++)
          racc[r2] -= Abt[p*16+r][p*16+r2] * w_;   // broadcast LDS read
      }
    }
    __syncthreads();
    if (wave > p){
      #pragma unroll
      for (int s16=0;s16<16;s16++){
        float w_ = sol[p*16+s16][lane];            // conflict-free (2 lanes/bank)
        #pragma unroll
        for (int r=0;r<16;r++)
          racc[r] -= Abt[p*16+s16][wave*16+r] * w_;
      }
    }
    __syncthreads();
  }

  // writeout W (over V) and U from sol
  {
    int row = tid>>2, qt = tid&3;
    if (qt < 2){
      #pragma unroll
      for (int i=0;i<8;i++){
        int col = qt*16 + i*2;
        unsigned int pk = (unsigned int)f2b(sol[row][col]) | ((unsigned int)f2b(sol[row][col+1])<<16);
        *(unsigned int*)(vwbuf + base + (size_t)row*128 + col) = pk;
      }
    } else {
      #pragma unroll
      for (int i=0;i<8;i++){
        int col = (qt-2)*16 + i*2;
        unsigned int pk = (unsigned int)f2b(sol[row][32+col]) | ((unsigned int)f2b(sol[row][33+col])<<16);
        *(unsigned int*)(Ubuf + ub + row*32 + col) = pk;
      }
    }
  }
}

// ---- phase B: one wave per (b,h), serial over 64 chunks.
// PREC=1: Sent stored f32; always: S and E applied as bf16 hi+lo pairs.
template<int PREC>
__global__ __launch_bounds__(64) void k_pB(const unsigned short* __restrict__ kbuf,
                                           unsigned short* webuf,
                                           const unsigned short* __restrict__ Ubuf,
                                           void* __restrict__ SentP){
  __shared__ float Sl[32][33];
  __shared__ unsigned short El[64][40];
  __shared__ unsigned short Ell[64][40];
  __shared__ unsigned short Kl[64][40];
  const int bh = blockIdx.x, b = bh>>2, h = bh&3;
  const int lane = threadIdx.x, fr = lane&15, fg = lane>>4;
  for (int i=lane; i<32*33; i+=64) ((float*)Sl)[i] = 0.f;
  f32x4 sc[2][2];
  #pragma unroll
  for (int it=0;it<2;it++){
    #pragma unroll
    for (int ct=0;ct<2;ct++) sc[it][ct]=(f32x4){0.f,0.f,0.f,0.f};
  }

  for (int c=0;c<NC;c++){
    const size_t base = ((size_t)b*TT + c*64)*128 + h*32;
    const size_t ub = ((size_t)bh*NC + c)*2048;
    {
      const unsigned short* kr = kbuf + base + (size_t)lane*128;
      const unsigned short* wr = webuf + base + (size_t)lane*128;
      uint4 a0=*(const uint4*)(kr),   a1=*(const uint4*)(kr+8);
      uint4 a2=*(const uint4*)(kr+16),a3=*(const uint4*)(kr+24);
      uint4 b0=*(const uint4*)(wr),   b1=*(const uint4*)(wr+8);
      uint4 b2=*(const uint4*)(wr+16),b3=*(const uint4*)(wr+24);
      *(uint4*)&Kl[lane][0]=a0; *(uint4*)&Kl[lane][8]=a1;
      *(uint4*)&Kl[lane][16]=a2; *(uint4*)&Kl[lane][24]=a3;
      *(uint4*)&El[lane][0]=b0; *(uint4*)&El[lane][8]=b1;
      *(uint4*)&El[lane][16]=b2; *(uint4*)&El[lane][24]=b3;
    }
    short8 uf[4];
    #pragma unroll
    for (int mt=0;mt<4;mt++)
      uf[mt] = *(const short8*)(Ubuf + ub + (size_t)(mt*16+fr)*32 + fg*8);
    // acc init = W
    f32x4 acc[4][2];
    #pragma unroll
    for (int mt=0;mt<4;mt++){
      #pragma unroll
      for (int ct=0;ct<2;ct++){
        #pragma unroll
        for (int r=0;r<4;r++)
          acc[mt][ct][r] = b2f(El[mt*16+fg*4+r][ct*16+fr]);
      }
    }
    // S B-frags as hi+lo of (-S); store S_entry (f32 if PREC)
    short8 sb[2], sbl[2];
    #pragma unroll
    for (int ct=0;ct<2;ct++){
      short8 neg, negl;
      float pos[8];
      #pragma unroll
      for (int jj=0;jj<8;jj++){
        float sv = Sl[fg*8+jj][ct*16+fr];
        pos[jj] = sv;
        float nv = -sv;
        unsigned short hi = f2b(nv);
        neg[jj]=(short)hi;
        negl[jj]=(short)f2b(nv - b2f(hi));
      }
      sb[ct]=neg; sbl[ct]=negl;
      if (PREC){
        float* Sf = (float*)SentP + ((size_t)bh*NC + c)*1024 + ct*512 + lane*8;
        *(float4*)Sf     = (float4){pos[0],pos[1],pos[2],pos[3]};
        *(float4*)(Sf+4) = (float4){pos[4],pos[5],pos[6],pos[7]};
      } else {
        short8 p8;
        #pragma unroll
        for (int jj=0;jj<8;jj++) p8[jj]=(short)f2b(pos[jj]);
        *(short8*)((unsigned short*)SentP + ((size_t)bh*NC + c)*1024 + ct*512 + lane*8) = p8;
      }
    }
    // E = W + U*(-S_hi) + U*(-S_lo)
    #pragma unroll
    for (int mt=0;mt<4;mt++){
      #pragma unroll
      for (int ct=0;ct<2;ct++){
        acc[mt][ct] = __builtin_amdgcn_mfma_f32_16x16x32_bf16(uf[mt], sb[ct],  acc[mt][ct],0,0,0);
        acc[mt][ct] = __builtin_amdgcn_mfma_f32_16x16x32_bf16(uf[mt], sbl[ct], acc[mt][ct],0,0,0);
      }
    }
    // write E hi (LDS+global) and E lo (LDS)
    #pragma unroll
    for (int mt=0;mt<4;mt++){
      #pragma unroll
      for (int ct=0;ct<2;ct++){
        #pragma unroll
        for (int r=0;r<4;r++){
          float ef = acc[mt][ct][r];
          unsigned short eh = f2b(ef);
          int t = mt*16+fg*4+r, j = ct*16+fr;
          El[t][j] = eh;
          Ell[t][j] = f2b(ef - b2f(eh));
          webuf[base + (size_t)t*128 + j] = eh;
        }
      }
    }
    // S += K^T (E_hi + E_lo)
    short8 ka[2][2], eb[2][2], ebl[2][2];
    #pragma unroll
    for (int it=0;it<2;it++){
      #pragma unroll
      for (int ks=0;ks<2;ks++){
        short8 tmp;
        #pragma unroll
        for (int jj=0;jj<8;jj++) tmp[jj] = (short)Kl[ks*32+fg*8+jj][it*16+fr];
        ka[it][ks]=tmp;
      }
    }
    #pragma unroll
    for (int ct=0;ct<2;ct++){
      #pragma unroll
      for (int ks=0;ks<2;ks++){
        short8 t1v, t2v;
        #pragma unroll
        for (int jj=0;jj<8;jj++){
          t1v[jj] = (short)El[ks*32+fg*8+jj][ct*16+fr];
          t2v[jj] = (short)Ell[ks*32+fg*8+jj][ct*16+fr];
        }
        eb[ct][ks]=t1v; ebl[ct][ks]=t2v;
      }
    }
    #pragma unroll
    for (int it=0;it<2;it++){
      #pragma unroll
      for (int ct=0;ct<2;ct++){
        #pragma unroll
        for (int ks=0;ks<2;ks++){
          sc[it][ct] = __builtin_amdgcn_mfma_f32_16x16x32_bf16(ka[it][ks], eb[ct][ks],  sc[it][ct],0,0,0);
          sc[it][ct] = __builtin_amdgcn_mfma_f32_16x16x32_bf16(ka[it][ks], ebl[ct][ks], sc[it][ct],0,0,0);
        }
      }
    }
    // master S (f32) back to Sl
    #pragma unroll
    for (int it=0;it<2;it++){
      #pragma unroll
      for (int ct=0;ct<2;ct++){
        #pragma unroll
        for (int r=0;r<4;r++)
          Sl[it*16+fg*4+r][ct*16+fr] = sc[it][ct][r];
      }
    }
  }
}

// ---- phase C: O = Q S_entry + tril(QK^T) E ; P applied as bf16 hi+lo ----
template<int PREC>
__global__ __launch_bounds__(64) void k_pC(unsigned short* qobuf,
                                           const unsigned short* __restrict__ kbuf,
                                           const unsigned short* __restrict__ ebuf,
                                           const void* __restrict__ SentP){
  __shared__ unsigned short Pl[64][72];
  __shared__ unsigned short Plo[64][72];
  __shared__ unsigned short El[64][40];
  const int c = blockIdx.x, bh = blockIdx.y, b=bh>>2, h=bh&3;
  const int lane=threadIdx.x, fr=lane&15, fg=lane>>4;
  const size_t base = ((size_t)b*TT + c*64)*128 + h*32;
  #pragma unroll
  for (int i=0;i<9;i++){
    *(uint4*)&Pl[lane][i*8]  = (uint4){0u,0u,0u,0u};
    *(uint4*)&Plo[lane][i*8] = (uint4){0u,0u,0u,0u};
  }
  {
    const unsigned short* er = ebuf + base + (size_t)lane*128;
    uint4 a0=*(const uint4*)(er),   a1=*(const uint4*)(er+8);
    uint4 a2=*(const uint4*)(er+16),a3=*(const uint4*)(er+24);
    *(uint4*)&El[lane][0]=a0; *(uint4*)&El[lane][8]=a1;
    *(uint4*)&El[lane][16]=a2; *(uint4*)&El[lane][24]=a3;
  }
  short8 qf[4], kf[4];
  #pragma unroll
  for (int mt=0;mt<4;mt++){
    qf[mt] = *(const short8*)(qobuf + base + (size_t)(mt*16+fr)*128 + fg*8);
    kf[mt] = *(const short8*)(kbuf  + base + (size_t)(mt*16+fr)*128 + fg*8);
  }
  // P = tril(QK^T) -> hi/lo
  #pragma unroll
  for (int mt=0;mt<4;mt++){
    #pragma unroll
    for (int nt=0;nt<4;nt++){
      if (nt>mt) continue;
      f32x4 p = (f32x4){0.f,0.f,0.f,0.f};
      p = __builtin_amdgcn_mfma_f32_16x16x32_bf16(qf[mt], kf[nt], p,0,0,0);
      #pragma unroll
      for (int r=0;r<4;r++){
        int t = mt*16+fg*4+r, s = nt*16+fr;
        float pv = p[r];
        unsigned short ph = f2b(pv);
        Pl[t][s]  = (s<=t)? ph : (unsigned short)0;
        Plo[t][s] = (s<=t)? f2b(pv - b2f(ph)) : (unsigned short)0;
      }
    }
  }
  // O = Q*S_entry
  f32x4 acc[4][2];
  #pragma unroll
  for (int mt=0;mt<4;mt++){
    #pragma unroll
    for (int ct=0;ct<2;ct++) acc[mt][ct]=(f32x4){0.f,0.f,0.f,0.f};
  }
  if (PREC){
    short8 sfh[2], sfl[2];
    #pragma unroll
    for (int ct=0;ct<2;ct++){
      const float* Sf = (const float*)SentP + ((size_t)bh*NC + c)*1024 + ct*512 + lane*8;
      float4 v0 = *(const float4*)Sf;
      float4 v1 = *(const float4*)(Sf+4);
      float sv[8] = {v0.x,v0.y,v0.z,v0.w,v1.x,v1.y,v1.z,v1.w};
      short8 hh, ll;
      #pragma unroll
      for (int jj=0;jj<8;jj++){
        unsigned short hi = f2b(sv[jj]);
        hh[jj]=(short)hi; ll[jj]=(short)f2b(sv[jj]-b2f(hi));
      }
      sfh[ct]=hh; sfl[ct]=ll;
    }
    #pragma unroll
    for (int mt=0;mt<4;mt++){
      #pragma unroll
      for (int ct=0;ct<2;ct++){
        acc[mt][ct]=__builtin_amdgcn_mfma_f32_16x16x32_bf16(qf[mt], sfh[ct], acc[mt][ct],0,0,0);
        acc[mt][ct]=__builtin_amdgcn_mfma_f32_16x16x32_bf16(qf[mt], sfl[ct], acc[mt][ct],0,0,0);
      }
    }
  } else {
    short8 sf[2];
    #pragma unroll
    for (int ct=0;ct<2;ct++)
      sf[ct] = *(const short8*)((const unsigned short*)SentP + ((size_t)bh*NC + c)*1024 + ct*512 + lane*8);
    #pragma unroll
    for (int mt=0;mt<4;mt++){
      #pragma unroll
      for (int ct=0;ct<2;ct++)
        acc[mt][ct]=__builtin_amdgcn_mfma_f32_16x16x32_bf16(qf[mt], sf[ct], acc[mt][ct],0,0,0);
    }
  }
  // O += (P_hi + P_lo)*E
  short8 ebf[2][2];
  #pragma unroll
  for (int ct=0;ct<2;ct++){
    #pragma unroll
    for (int ks=0;ks<2;ks++){
      short8 tmp;
      #pragma unroll
      for (int jj=0;jj<8;jj++) tmp[jj]=(short)El[ks*32+fg*8+jj][ct*16+fr];
      ebf[ct][ks]=tmp;
    }
  }
  #pragma unroll
  for (int mt=0;mt<4;mt++){
    #pragma unroll
    for (int ks=0;ks<2;ks++){
      short8 pa  = *(const short8*)&Pl[mt*16+fr][ks*32+fg*8];
      short8 pal = *(const short8*)&Plo[mt*16+fr][ks*32+fg*8];
      #pragma unroll
      for (int ct=0;ct<2;ct++){
        acc[mt][ct]=__builtin_amdgcn_mfma_f32_16x16x32_bf16(pa,  ebf[ct][ks], acc[mt][ct],0,0,0);
        acc[mt][ct]=__builtin_amdgcn_mfma_f32_16x16x32_bf16(pal, ebf[ct][ks], acc[mt][ct],0,0,0);
      }
    }
  }
  // store O over Q
  #pragma unroll
  for (int mt=0;mt<4;mt++){
    #pragma unroll
    for (int ct=0;ct<2;ct++){
      #pragma unroll
      for (int r=0;r<4;r++)
        qobuf[base + (size_t)(mt*16+fg*4+r)*128 + ct*16+fr] = f2b(acc[mt][ct][r]);
    }
  }
}

// ---------------- fallback sequential scan ----------------
__global__ __launch_bounds__(64) void k_scan(const unsigned short* q, const unsigned short* k,
                                             const unsigned short* v, const float* beta,
                                             unsigned short* o){
  int b = blockIdx.x>>2, hh = blockIdx.x&3;
  int lane = threadIdx.x;
  int j = lane&31, ih = lane>>5;
  float S[16];
  #pragma unroll
  for (int m=0;m<16;m++) S[m]=0.f;
  size_t idx0 = ((size_t)b*TT*HH + hh)*dh;
  size_t bidx0 = (size_t)b*TT*HH + hh;
  const unsigned short* kp = k + idx0 + ih*16;
  const unsigned short* qp = q + idx0 + ih*16;
  for (int t=0;t<TT;t++){
    size_t ofs=(size_t)t*128;
    uint4 ka=*(const uint4*)(kp+ofs), kb=*(const uint4*)(kp+ofs+8);
    uint4 qa=*(const uint4*)(qp+ofs), qb=*(const uint4*)(qp+ofs+8);
    float kf[16], qf[16];
    kf[0]=blo(ka.x);kf[1]=bhi(ka.x);kf[2]=blo(ka.y);kf[3]=bhi(ka.y);
    kf[4]=blo(ka.z);kf[5]=bhi(ka.z);kf[6]=blo(ka.w);kf[7]=bhi(ka.w);
    kf[8]=blo(kb.x);kf[9]=bhi(kb.x);kf[10]=blo(kb.y);kf[11]=bhi(kb.y);
    kf[12]=blo(kb.z);kf[13]=bhi(kb.z);kf[14]=blo(kb.w);kf[15]=bhi(kb.w);
    qf[0]=blo(qa.x);qf[1]=bhi(qa.x);qf[2]=blo(qa.y);qf[3]=bhi(qa.y);
    qf[4]=blo(qa.z);qf[5]=bhi(qa.z);qf[6]=blo(qa.w);qf[7]=bhi(qa.w);
    qf[8]=blo(qb.x);qf[9]=bhi(qb.x);qf[10]=blo(qb.y);qf[11]=bhi(qb.y);
    qf[12]=blo(qb.z);qf[13]=bhi(qb.z);qf[14]=blo(qb.w);qf[15]=bhi(qb.w);
    float vc = b2f(v[idx0+ofs+j]), bc = beta[bidx0+(size_t)t*4];
    float p0=0,p1=0,p2=0,p3=0;
    #pragma unroll
    for (int m=0;m<4;m++){
      p0 += S[m]*kf[m]; p1 += S[m+4]*kf[m+4]; p2 += S[m+8]*kf[m+8]; p3 += S[m+12]*kf[m+12];
    }
    float p = (p0+p1)+(p2+p3);
    p += __shfl_xor(p, 32, 64);
    float err = (vc - p)*bc;
    float o0=0,o1=0,o2=0,o3=0;
    #pragma unroll
    for (int m=0;m<4;m++){
      S[m]    += kf[m]*err;     o0 += S[m]*qf[m];
      S[m+4]  += kf[m+4]*err;   o1 += S[m+4]*qf[m+4];
      S[m+8]  += kf[m+8]*err;   o2 += S[m+8]*qf[m+8];
      S[m+12] += kf[m+12]*err;  o3 += S[m+12]*qf[m+12];
    }
    float oo = (o0+o1)+(o2+o3);
    oo += __shfl_xor(oo, 32, 64);
    if (ih==0) o[idx0 + ofs + j] = f2b(oo);
  }
}

// ---------------- o = rms(o, hnw)*silu(gate) ----------------
__global__ __launch_bounds__(256) void k_ogate(const unsigned short* __restrict__ o, const unsigned short* __restrict__ gate,
                                               const float* __restrict__ hnwl, unsigned short* __restrict__ tmp){
  int tid=threadIdx.x;
  size_t bt = (size_t)blockIdx.x*2 + (tid>>7);
  int c = tid&127;
  size_t i = bt*DD + c;
  float ov = b2f(o[i]);
  float ss = ov*ov;
  #pragma unroll
  for (int m=1;m<32;m<<=1) ss += __shfl_xor(ss,m,64);
  float r = rsqrtf(ss*(1.0f/32.0f)+1e-5f);
  float g = b2f(gate[i]);
  tmp[i] = f2b(ov*r*hnwl[c&31]*siluf(g));
}

// ---------------- final head ----------------
__global__ __launch_bounds__(256) void k_head(const unsigned short* __restrict__ hf, const float* __restrict__ hw,
                                              float* __restrict__ out){
  int gid = blockIdx.x*256+threadIdx.x;
  if (gid >= MM*VV) return;
  int row = gid/VV, n = gid - row*VV;
  const unsigned short* a = hf + (size_t)row*DD;
  const float* w = hw + n*DD;
  float s=0.f;
  #pragma unroll
  for (int k2=0;k2<128;k2+=8){
    uint4 av = *(const uint4*)(a+k2);
    float4 wa = *(const float4*)(w+k2);
    float4 wb = *(const float4*)(w+k2+4);
    s += blo(av.x)*wa.x + bhi(av.x)*wa.y + blo(av.y)*wa.z + bhi(av.y)*wa.w;
    s += blo(av.z)*wb.x + bhi(av.z)*wb.y + blo(av.w)*wb.z + bhi(av.w)*wb.w;
  }
  out[gid] = s;
}

extern "C" void kernel_launch(void* const* d_in, const int* in_sizes, int n_in,
                              void* d_out, int out_size, void* d_ws, size_t ws_size,
                              hipStream_t stream){
  const int*   x   = (const int*)d_in[0];
  const float* emb = (const float*)d_in[1];
  const float* qw  = (const float*)d_in[2];
  const float* kw  = (const float*)d_in[3];
  const float* vw  = (const float*)d_in[4];
  const float* qcw = (const float*)d_in[5];
  const float* qcb = (const float*)d_in[6];
  const float* kcw = (const float*)d_in[7];
  const float* kcb = (const float*)d_in[8];
  const float* vcw = (const float*)d_in[9];
  const float* vcb = (const float*)d_in[10];
  const float* ow  = (const float*)d_in[11];
  const float* gw  = (const float*)d_in[12];
  const float* bw  = (const float*)d_in[13];
  const float* hnw = (const float*)d_in[14];
  const float* n1w = (const float*)d_in[15];
  const float* n2w = (const float*)d_in[16];
  const float* m1w = (const float*)d_in[17];
  const float* m2w = (const float*)d_in[18];
  const float* fnw = (const float*)d_in[19];
  const float* hw  = (const float*)d_in[20];

  // ws layout: h | hn | A | B | C | beta | halo | U | Sent(f32 or bf16)
  char* ws = (char*)d_ws;
  size_t off = 0;
  float* h             = (float*)(ws+off);          off += (size_t)MM*DD*4;
  unsigned short* hn   = (unsigned short*)(ws+off); off += (size_t)MM*DD*2;
  unsigned short* A    = (unsigned short*)(ws+off); off += (size_t)MM*DD*2;
  unsigned short* B    = (unsigned short*)(ws+off); off += (size_t)MM*DD*2;
  unsigned short* C    = (unsigned short*)(ws+off); off += (size_t)MM*DD*2;
  float* beta          = (float*)(ws+off);          off += (size_t)MM*HH*4;
  unsigned short* halo = (unsigned short*)(ws+off); off += (size_t)NCHUNK*9*128*2;
  unsigned short* U    = (unsigned short*)(ws+off); off += (size_t)MM*DD*2;      // 8192 chunks * 2048
  void* SentP          = (void*)(ws+off);
  const size_t NEED1 = off + (size_t)8192*1024*4;   // f32 Sent
  const size_t NEED0 = off + (size_t)8192*1024*2;   // bf16 Sent
  unsigned short* t1   = A;
  const int mode = (ws_size >= NEED1) ? 1 : (ws_size >= NEED0) ? 0 : -1;

  k_embed<<<MM*DD/256, 256, 0, stream>>>(x, emb, h);
  for (int l=0;l<LL;l++){
    k_rms<<<MM/4,256,0,stream>>>(h, n1w + l*DD, hn);
    k_gemm<0,0><<<dim3(MM/128,2),256,0,stream>>>(hn, qw + l*DD*DD, A, 128, 128);
    k_gemm<0,0><<<dim3(MM/128,2),256,0,stream>>>(hn, kw + l*DD*DD, B, 128, 128);
    k_gemm<0,0><<<dim3(MM/128,2),256,0,stream>>>(hn, vw + l*DD*DD, C, 128, 128);
    k_beta<<<MM/64,256,0,stream>>>(hn, bw + l*HH*DD, beta);
    k_halo<<<NCHUNK*9*128/256,256,0,stream>>>(A, B, C, halo);
    k_conv_ip<<<dim3(NCHUNK,3),256,0,stream>>>(A, B, C,
                                  qcw+l*DD*4, qcb+l*DD, kcw+l*DD*4, kcb+l*DD, vcw+l*DD*4, vcb+l*DD,
                                  halo);
    if (mode >= 0){
      k_pA<<<dim3(NC, BB*HH), 256, 0, stream>>>(B, C, beta, U);
      if (mode==1){
        k_pB<1><<<BB*HH, 64, 0, stream>>>(B, C, U, SentP);
        k_pC<1><<<dim3(NC, BB*HH), 64, 0, stream>>>(A, B, C, SentP);
      } else {
        k_pB<0><<<BB*HH, 64, 0, stream>>>(B, C, U, SentP);
        k_pC<0><<<dim3(NC, BB*HH), 64, 0, stream>>>(A, B, C, SentP);
      }
    } else {
      k_scan<<<BB*HH,64,0,stream>>>(A, B, C, beta, A);
    }
    k_gemm<0,0><<<dim3(MM/128,2),256,0,stream>>>(hn, gw + l*DD*DD, C, 128, 128);
    k_ogate<<<MM/2,256,0,stream>>>(A, C, hnw+l*dh, B);
    k_gemm<0,1><<<dim3(MM/128,2),256,0,stream>>>(B, ow + l*DD*DD, h, 128, 128);
    k_rms<<<MM/4,256,0,stream>>>(h, n2w + l*DD, hn);
    k_gemm<1,0><<<dim3(MM/128,4),256,0,stream>>>(hn, m1w + l*2*DD*DD, t1, 256, 128);
    k_gemm<0,1><<<dim3(MM/128,2),256,0,stream>>>(t1, m2w + l*2*DD*DD, h, 128, 256);
  }
  k_rms<<<MM/4,256,0,stream>>>(h, fnw, hn);
  k_head<<<(MM*VV+255)/256,256,0,stream>>>(hn, hw, (float*)d_out);
}

// Round 9
// 2831.333 us; speedup vs baseline: 2.5793x; 1.1645x over previous
//
#include <hip/hip_runtime.h>
#include <hip/hip_bf16.h>
#include <math.h>

#define BB 32
#define TT 4096
#define DD 128
#define HH 4
#define dh 32
#define VV 33
#define LL 4
#define MM (BB*TT)   // 131072 rows
#define NCHUNK (MM/128)  // 1024
#define NC 64        // delta chunks per (b,h): TT/64

typedef short short8 __attribute__((ext_vector_type(8)));
typedef float f32x4 __attribute__((ext_vector_type(4)));

__device__ __forceinline__ float b2f(unsigned short u){
  union{float f; unsigned int x;} v; v.x = ((unsigned int)u)<<16; return v.f;
}
__device__ __forceinline__ unsigned short f2b(float f){
  union{float f; unsigned int x;} v; v.f=f;
  unsigned int r = v.x + 0x7fffu + ((v.x>>16)&1u);
  return (unsigned short)(r>>16);
}
__device__ __forceinline__ float blo(unsigned int u){ union{float f;unsigned int x;}v; v.x=u<<16; return v.f;}
__device__ __forceinline__ float bhi(unsigned int u){ union{float f;unsigned int x;}v; v.x=u&0xffff0000u; return v.f;}
__device__ __forceinline__ float siluf(float x){ return x/(1.0f+expf(-x)); }

// ---------------- embedding ----------------
__global__ __launch_bounds__(256) void k_embed(const int* __restrict__ x, const float* __restrict__ emb,
                                               float* __restrict__ h){
  int i = blockIdx.x*256 + threadIdx.x;
  int bt = i>>7, c = i&127;
  h[i] = emb[x[bt]*DD + c];
}

// ---------------- rms norm ----------------
__global__ __launch_bounds__(256) void k_rms(const float* __restrict__ src, const float* __restrict__ w,
                                             unsigned short* __restrict__ dst){
  int row = blockIdx.x*4 + (threadIdx.x>>6);
  int lane = threadIdx.x&63;
  const float2 xv = *(const float2*)(src + (size_t)row*DD + lane*2);
  float ss = xv.x*xv.x + xv.y*xv.y;
  #pragma unroll
  for (int m=1;m<64;m<<=1) ss += __shfl_xor(ss,m,64);
  float sc = rsqrtf(ss*(1.0f/128.0f)+1e-5f);
  const float2 wv = *(const float2*)(w + lane*2);
  unsigned int o = ((unsigned int)f2b(xv.y*sc*wv.y)<<16) | (unsigned int)f2b(xv.x*sc*wv.x);
  *(unsigned int*)(dst + (size_t)row*DD + lane*2) = o;
}

// ---------------- MFMA GEMM, panel-looped: out[M,N] = A[M,K] @ W[N,K]^T ----------------
// A-tile (128 x 128 bf16) staged ONCE per K-chunk, then NP column panels of 64
// computed in sequence (acc[p] held in VGPRs). Grid: (M/128, N/(64*NP)).
template<int NP, int ACT, int OUTADD>
__global__ __launch_bounds__(256) void k_gemm(const unsigned short* __restrict__ A,
                                              const float* __restrict__ W,
                                              void* __restrict__ outp, int N, int K){
  __shared__ __align__(16) unsigned short As[128*128];
  __shared__ __align__(16) unsigned short Ws[64*128];
  const int tid = threadIdx.x;
  const int lane = tid & 63, wave = tid >> 6;
  const int row0 = blockIdx.x*128, colbase = blockIdx.y*(64*NP);
  const int wr0 = (wave&1)*64, wc0 = (wave>>1)*32;
  const int fr = lane & 15, fq = lane >> 4;
  f32x4 acc[NP][4][2];
  #pragma unroll
  for (int p=0;p<NP;p++)
    #pragma unroll
    for (int m=0;m<4;m++)
      #pragma unroll
      for (int n=0;n<2;n++) acc[p][m][n] = (f32x4){0.f,0.f,0.f,0.f};

  for (int kc=0; kc<K; kc+=128){
    #pragma unroll
    for (int ii=0; ii<8; ++ii){             // stage A tile
      int flat = tid + ii*256;
      int r = flat>>4, g = flat&15;
      uint4 gv = *(const uint4*)(A + (size_t)(row0+r)*K + kc + g*8);
      *(uint4*)&As[r*128 + ((g^(r&7))<<3)] = gv;
    }
    #pragma unroll
    for (int p=0;p<NP;p++){
      const int col0 = colbase + p*64;
      #pragma unroll
      for (int ii=0; ii<8; ++ii){           // stage W panel
        int flat = tid + ii*256;
        int n = flat>>5, q4 = flat&31;
        float4 wv = *(const float4*)(W + (size_t)(col0+n)*K + kc + q4*4);
        uint2 pk;
        pk.x = (unsigned int)f2b(wv.x) | ((unsigned int)f2b(wv.y)<<16);
        pk.y = (unsigned int)f2b(wv.z) | ((unsigned int)f2b(wv.w)<<16);
        int dst = n*128 + ((((q4>>1)^(n&7))<<3) | ((q4&1)<<2));
        *(uint2*)&Ws[dst] = pk;
      }
      __syncthreads();
      #pragma unroll
      for (int ks=0; ks<4; ++ks){
        int gg = ks*4 + fq;
        short8 a[4], b[2];
        #pragma unroll
        for (int m=0;m<4;m++){
          int row = wr0 + m*16 + fr;
          a[m] = *(const short8*)&As[row*128 + ((gg^(row&7))<<3)];
        }
        #pragma unroll
        for (int n=0;n<2;n++){
          int col = wc0 + n*16 + fr;
          b[n] = *(const short8*)&Ws[col*128 + ((gg^(col&7))<<3)];
        }
        #pragma unroll
        for (int m=0;m<4;m++){
          #pragma unroll
          for (int n=0;n<2;n++)
            acc[p][m][n] = __builtin_amdgcn_mfma_f32_16x16x32_bf16(a[m], b[n], acc[p][m][n], 0, 0, 0);
        }
      }
      __syncthreads();                      // safe for next W/A staging
    }
  }

  #pragma unroll
  for (int p=0;p<NP;p++){
    const int col0 = colbase + p*64;
    if (OUTADD){
      float* O = (float*)outp;
      #pragma unroll
      for (int m=0;m<4;m++){
        #pragma unroll
        for (int n=0;n<2;n++){
          int ccol = col0 + wc0 + n*16 + fr;
          #pragma unroll
          for (int r=0;r<4;r++){
            int rrow = row0 + wr0 + m*16 + fq*4 + r;
            O[(size_t)rrow*N + ccol] += acc[p][m][n][r];
          }
        }
      }
    } else {
      unsigned short* O = (unsigned short*)outp;
      #pragma unroll
      for (int m=0;m<4;m++){
        #pragma unroll
        for (int n=0;n<2;n++){
          int ccol = col0 + wc0 + n*16 + fr;
          #pragma unroll
          for (int r=0;r<4;r++){
            int rrow = row0 + wr0 + m*16 + fq*4 + r;
            float vv = acc[p][m][n][r];
            if (ACT) vv = siluf(vv);
            O[(size_t)rrow*N + ccol] = f2b(vv);
          }
        }
      }
    }
  }
}

// ---------------- MFMA head: out[M,33] = hn[M,128] @ hw[33,128]^T ----------------
__global__ __launch_bounds__(256) void k_headm(const unsigned short* __restrict__ A,
                                               const float* __restrict__ W,
                                               float* __restrict__ out){
  __shared__ __align__(16) unsigned short As[128*128];
  __shared__ __align__(16) unsigned short Ws[64*128];
  const int tid = threadIdx.x;
  const int lane = tid & 63, wave = tid >> 6;
  const int row0 = blockIdx.x*128;
  const int wr0 = (wave&1)*64, wc0 = (wave>>1)*32;
  const int fr = lane & 15, fq = lane >> 4;
  f32x4 acc[4][2];
  #pragma unroll
  for (int m=0;m<4;m++)
    #pragma unroll
    for (int n=0;n<2;n++) acc[m][n] = (f32x4){0.f,0.f,0.f,0.f};

  #pragma unroll
  for (int ii=0; ii<8; ++ii){
    int flat = tid + ii*256;
    int r = flat>>4, g = flat&15;
    uint4 gv = *(const uint4*)(A + (size_t)(row0+r)*DD + g*8);
    *(uint4*)&As[r*128 + ((g^(r&7))<<3)] = gv;
  }
  #pragma unroll
  for (int ii=0; ii<8; ++ii){
    int flat = tid + ii*256;
    int n = flat>>5, q4 = flat&31;
    float4 wv = (n < VV) ? *(const float4*)(W + (size_t)n*DD + q4*4)
                         : (float4){0.f,0.f,0.f,0.f};
    uint2 pk;
    pk.x = (unsigned int)f2b(wv.x) | ((unsigned int)f2b(wv.y)<<16);
    pk.y = (unsigned int)f2b(wv.z) | ((unsigned int)f2b(wv.w)<<16);
    int dst = n*128 + ((((q4>>1)^(n&7))<<3) | ((q4&1)<<2));
    *(uint2*)&Ws[dst] = pk;
  }
  __syncthreads();
  #pragma unroll
  for (int ks=0; ks<4; ++ks){
    int gg = ks*4 + fq;
    short8 a[4], b[2];
    #pragma unroll
    for (int m=0;m<4;m++){
      int row = wr0 + m*16 + fr;
      a[m] = *(const short8*)&As[row*128 + ((gg^(row&7))<<3)];
    }
    #pragma unroll
    for (int n=0;n<2;n++){
      int col = wc0 + n*16 + fr;
      b[n] = *(const short8*)&Ws[col*128 + ((gg^(col&7))<<3)];
    }
    #pragma unroll
    for (int m=0;m<4;m++){
      #pragma unroll
      for (int n=0;n<2;n++)
        acc[m][n] = __builtin_amdgcn_mfma_f32_16x16x32_bf16(a[m], b[n], acc[m][n], 0, 0, 0);
    }
  }
  #pragma unroll
  for (int m=0;m<4;m++){
    #pragma unroll
    for (int n=0;n<2;n++){
      int ccol = wc0 + n*16 + fr;
      if (ccol < VV){
        #pragma unroll
        for (int r=0;r<4;r++){
          int rrow = row0 + wr0 + m*16 + fq*4 + r;
          out[(size_t)rrow*VV + ccol] = acc[m][n][r];
        }
      }
    }
  }
}

// ---------------- beta = sigmoid(hn @ bw^T), N=4 ----------------
__global__ __launch_bounds__(256) void k_beta(const unsigned short* __restrict__ hn,
                                              const float* __restrict__ bwl, float* __restrict__ beta){
  __shared__ unsigned short As[64*128];
  int tid = threadIdx.x; int row0 = blockIdx.x*64;
  #pragma unroll
  for (int ii=0;ii<4;ii++){
    int flat = tid + ii*256;
    int r = flat>>4, v16 = flat&15;
    *(uint4*)&As[r*128 + v16*8] = *(const uint4*)(hn + (size_t)(row0+r)*DD + v16*8);
  }
  __syncthreads();
  int r = tid>>2, n = tid&3;
  const float* wr = bwl + n*DD;
  const unsigned short* ar = &As[r*128];
  float s = 0.f;
  #pragma unroll
  for (int k=0;k<128;k+=8){
    uint4 a = *(const uint4*)(ar + k);
    float4 wa = *(const float4*)(wr + k);
    float4 wb = *(const float4*)(wr + k + 4);
    s += blo(a.x)*wa.x + bhi(a.x)*wa.y + blo(a.y)*wa.z + bhi(a.y)*wa.w;
    s += blo(a.z)*wb.x + bhi(a.z)*wb.y + blo(a.w)*wb.z + bhi(a.w)*wb.w;
  }
  beta[(size_t)(row0+r)*HH + n] = 1.0f/(1.0f+expf(-s));
}

// ---------------- halo save ----------------
__global__ __launch_bounds__(256) void k_halo(const unsigned short* __restrict__ A,
                                              const unsigned short* __restrict__ B,
                                              const unsigned short* __restrict__ C,
                                              unsigned short* __restrict__ halo){
  int i = blockIdx.x*256 + threadIdx.x;
  int ch = i & 127;
  int rt = i >> 7;
  int r3 = rt % 3;
  int tn = (rt/3) % 3;
  int ck = rt / 9;
  unsigned short v = 0;
  if ((ck & 31) != 0){
    const unsigned short* X = (tn==0) ? A : (tn==1) ? B : C;
    v = X[((size_t)ck*128 - 3 + r3)*DD + ch];
  }
  halo[(size_t)i] = v;
}

// ---------------- in-place causal conv(4)+silu(+l2n) ----------------
__global__ __launch_bounds__(256) void k_conv_ip(
    unsigned short* __restrict__ A, unsigned short* __restrict__ B, unsigned short* __restrict__ C,
    const float* __restrict__ qcw, const float* __restrict__ qcb,
    const float* __restrict__ kcw, const float* __restrict__ kcb,
    const float* __restrict__ vcw, const float* __restrict__ vcb,
    const unsigned short* __restrict__ halo){
  __shared__ __align__(16) unsigned short Xs[131*128];
  const int tid = threadIdx.x;
  const int ck = blockIdx.x, tn = blockIdx.y;
  unsigned short* X = (tn==0) ? A : (tn==1) ? B : C;
  const float* w = (tn==0) ? qcw : (tn==1) ? kcw : vcw;
  const float* bi = (tn==0) ? qcb : (tn==1) ? kcb : vcb;

  if (tid < 48){
    int lr = tid>>4, c16 = tid&15;
    *(uint4*)&Xs[lr*128 + c16*8] = *(const uint4*)&halo[((size_t)(ck*3+tn)*3 + lr)*128 + c16*8];
  }
  #pragma unroll
  for (int ii=0; ii<8; ++ii){
    int flat = tid + ii*256;
    int r = flat>>4, c16 = flat&15;
    *(uint4*)&Xs[(3+r)*128 + c16*8] = *(const uint4*)&X[((size_t)ck*128 + r)*DD + c16*8];
  }
  __syncthreads();

  const int rh = tid>>7, c = tid&127;
  float w0=w[c*4+0], w1=w[c*4+1], w2=w[c*4+2], w3=w[c*4+3];
  float bc = bi[c];
  #pragma unroll 2
  for (int rr=0; rr<64; ++rr){
    int row = rr*2 + rh;
    float y = bc + w0*b2f(Xs[(row+0)*128+c]) + w1*b2f(Xs[(row+1)*128+c])
                 + w2*b2f(Xs[(row+2)*128+c]) + w3*b2f(Xs[(row+3)*128+c]);
    y = siluf(y);
    if (tn < 2){
      float s = y*y;
      #pragma unroll
      for (int m=1;m<32;m<<=1) s += __shfl_xor(s,m,64);
      y *= rsqrtf(s + 1e-6f);
      if (tn==0) y *= 0.17677669529663687f;
    }
    X[((size_t)ck*128 + row)*DD + c] = f2b(y);
  }
}

// ======================= chunked delta-rule (WY form) =======================
// ---- phase A (v3): 4-wave cooperative blocked forward substitution ----
__global__ __launch_bounds__(256) void k_pA(const unsigned short* __restrict__ kbuf,
                                            unsigned short* vwbuf,
                                            const float* __restrict__ betab,
                                            unsigned short* __restrict__ Ubuf){
  __shared__ float Abt[64][68];   // [s][t]
  __shared__ float sol[64][72];   // [t][col]  col<32: W, col>=32: U
  __shared__ float bs[64];
  const int c = blockIdx.x, bh = blockIdx.y;
  const int b = bh>>2, h = bh&3;
  const int tid = threadIdx.x;
  const int wave = tid>>6, lane = tid&63;
  const int fr = lane&15, fg = lane>>4;
  const size_t base = ((size_t)b*TT + c*64)*128 + h*32;
  const size_t bbase = ((size_t)b*TT + c*64)*4 + h;
  const size_t ub = ((size_t)bh*NC + c)*2048;

  if (tid < 64) bs[tid] = betab[bbase + (size_t)tid*4];

  short8 kA  = *(const short8*)(kbuf + base + (size_t)(wave*16+fr)*128 + fg*8);
  short8 kB0 = *(const short8*)(kbuf + base + (size_t)( 0+fr)*128 + fg*8);
  short8 kB1 = *(const short8*)(kbuf + base + (size_t)(16+fr)*128 + fg*8);
  short8 kB2 = *(const short8*)(kbuf + base + (size_t)(32+fr)*128 + fg*8);
  short8 kB3 = *(const short8*)(kbuf + base + (size_t)(48+fr)*128 + fg*8);
  __syncthreads();   // bs visible

  {
    float4 bsv = *(const float4*)&bs[wave*16 + fg*4];
    f32x4 a;
    #define BUILD(nt, kB) if (wave >= nt){ \
      a = (f32x4){0.f,0.f,0.f,0.f}; \
      a = __builtin_amdgcn_mfma_f32_16x16x32_bf16(kA, kB, a, 0,0,0); \
      Abt[nt*16+fr][wave*16+fg*4+0] = a[0]*bsv.x; \
      Abt[nt*16+fr][wave*16+fg*4+1] = a[1]*bsv.y; \
      Abt[nt*16+fr][wave*16+fg*4+2] = a[2]*bsv.z; \
      Abt[nt*16+fr][wave*16+fg*4+3] = a[3]*bsv.w; }
    BUILD(0, kB0) BUILD(1, kB1) BUILD(2, kB2) BUILD(3, kB3)
    #undef BUILD
  }

  const unsigned short* xp = ((lane<32)? (const unsigned short*)vwbuf : kbuf) + base + (lane&31);
  float racc[16];
  #pragma unroll
  for (int r=0;r<16;r++)
    racc[r] = b2f(xp[(size_t)(wave*16+r)*128]) * bs[wave*16+r];

  #pragma unroll
  for (int p=0;p<4;p++){
    if (wave == p){
      #pragma unroll
      for (int r=0;r<16;r++){
        float w_ = racc[r];
        sol[p*16+r][lane] = w_;
        #pragma unroll
        for (int r2=r+1;r2<16;r2++)
          racc[r2] -= Abt[p*16+r][p*16+r2] * w_;
      }
    }
    __syncthreads();
    if (wave > p){
      #pragma unroll
      for (int s16=0;s16<16;s16++){
        float w_ = sol[p*16+s16][lane];
        #pragma unroll
        for (int r=0;r<16;r++)
          racc[r] -= Abt[p*16+s16][wave*16+r] * w_;
      }
    }
    __syncthreads();
  }

  {
    int row = tid>>2, qt = tid&3;
    if (qt < 2){
      #pragma unroll
      for (int i=0;i<8;i++){
        int col = qt*16 + i*2;
        unsigned int pk = (unsigned int)f2b(sol[row][col]) | ((unsigned int)f2b(sol[row][col+1])<<16);
        *(unsigned int*)(vwbuf + base + (size_t)row*128 + col) = pk;
      }
    } else {
      #pragma unroll
      for (int i=0;i<8;i++){
        int col = (qt-2)*16 + i*2;
        unsigned int pk = (unsigned int)f2b(sol[row][32+col]) | ((unsigned int)f2b(sol[row][33+col])<<16);
        *(unsigned int*)(Ubuf + ub + row*32 + col) = pk;
      }
    }
  }
}

// ---- phase B: one wave per (b,h), serial over 64 chunks ----
template<int PREC>
__global__ __launch_bounds__(64) void k_pB(const unsigned short* __restrict__ kbuf,
                                           unsigned short* webuf,
                                           const unsigned short* __restrict__ Ubuf,
                                           void* __restrict__ SentP){
  __shared__ float Sl[32][33];
  __shared__ unsigned short El[64][40];
  __shared__ unsigned short Ell[64][40];
  __shared__ unsigned short Kl[64][40];
  const int bh = blockIdx.x, b = bh>>2, h = bh&3;
  const int lane = threadIdx.x, fr = lane&15, fg = lane>>4;
  for (int i=lane; i<32*33; i+=64) ((float*)Sl)[i] = 0.f;
  f32x4 sc[2][2];
  #pragma unroll
  for (int it=0;it<2;it++){
    #pragma unroll
    for (int ct=0;ct<2;ct++) sc[it][ct]=(f32x4){0.f,0.f,0.f,0.f};
  }

  for (int c=0;c<NC;c++){
    const size_t base = ((size_t)b*TT + c*64)*128 + h*32;
    const size_t ub = ((size_t)bh*NC + c)*2048;
    {
      const unsigned short* kr = kbuf + base + (size_t)lane*128;
      const unsigned short* wr = webuf + base + (size_t)lane*128;
      uint4 a0=*(const uint4*)(kr),   a1=*(const uint4*)(kr+8);
      uint4 a2=*(const uint4*)(kr+16),a3=*(const uint4*)(kr+24);
      uint4 b0=*(const uint4*)(wr),   b1=*(const uint4*)(wr+8);
      uint4 b2=*(const uint4*)(wr+16),b3=*(const uint4*)(wr+24);
      *(uint4*)&Kl[lane][0]=a0; *(uint4*)&Kl[lane][8]=a1;
      *(uint4*)&Kl[lane][16]=a2; *(uint4*)&Kl[lane][24]=a3;
      *(uint4*)&El[lane][0]=b0; *(uint4*)&El[lane][8]=b1;
      *(uint4*)&El[lane][16]=b2; *(uint4*)&El[lane][24]=b3;
    }
    short8 uf[4];
    #pragma unroll
    for (int mt=0;mt<4;mt++)
      uf[mt] = *(const short8*)(Ubuf + ub + (size_t)(mt*16+fr)*32 + fg*8);
    f32x4 acc[4][2];
    #pragma unroll
    for (int mt=0;mt<4;mt++){
      #pragma unroll
      for (int ct=0;ct<2;ct++){
        #pragma unroll
        for (int r=0;r<4;r++)
          acc[mt][ct][r] = b2f(El[mt*16+fg*4+r][ct*16+fr]);
      }
    }
    short8 sb[2], sbl[2];
    #pragma unroll
    for (int ct=0;ct<2;ct++){
      short8 neg, negl;
      float pos[8];
      #pragma unroll
      for (int jj=0;jj<8;jj++){
        float sv = Sl[fg*8+jj][ct*16+fr];
        pos[jj] = sv;
        float nv = -sv;
        unsigned short hi = f2b(nv);
        neg[jj]=(short)hi;
        negl[jj]=(short)f2b(nv - b2f(hi));
      }
      sb[ct]=neg; sbl[ct]=negl;
      if (PREC){
        float* Sf = (float*)SentP + ((size_t)bh*NC + c)*1024 + ct*512 + lane*8;
        *(float4*)Sf     = (float4){pos[0],pos[1],pos[2],pos[3]};
        *(float4*)(Sf+4) = (float4){pos[4],pos[5],pos[6],pos[7]};
      } else {
        short8 p8;
        #pragma unroll
        for (int jj=0;jj<8;jj++) p8[jj]=(short)f2b(pos[jj]);
        *(short8*)((unsigned short*)SentP + ((size_t)bh*NC + c)*1024 + ct*512 + lane*8) = p8;
      }
    }
    #pragma unroll
    for (int mt=0;mt<4;mt++){
      #pragma unroll
      for (int ct=0;ct<2;ct++){
        acc[mt][ct] = __builtin_amdgcn_mfma_f32_16x16x32_bf16(uf[mt], sb[ct],  acc[mt][ct],0,0,0);
        acc[mt][ct] = __builtin_amdgcn_mfma_f32_16x16x32_bf16(uf[mt], sbl[ct], acc[mt][ct],0,0,0);
      }
    }
    #pragma unroll
    for (int mt=0;mt<4;mt++){
      #pragma unroll
      for (int ct=0;ct<2;ct++){
        #pragma unroll
        for (int r=0;r<4;r++){
          float ef = acc[mt][ct][r];
          unsigned short eh = f2b(ef);
          int t = mt*16+fg*4+r, j = ct*16+fr;
          El[t][j] = eh;
          Ell[t][j] = f2b(ef - b2f(eh));
          webuf[base + (size_t)t*128 + j] = eh;
        }
      }
    }
    short8 ka[2][2], eb[2][2], ebl[2][2];
    #pragma unroll
    for (int it=0;it<2;it++){
      #pragma unroll
      for (int ks=0;ks<2;ks++){
        short8 tmp;
        #pragma unroll
        for (int jj=0;jj<8;jj++) tmp[jj] = (short)Kl[ks*32+fg*8+jj][it*16+fr];
        ka[it][ks]=tmp;
      }
    }
    #pragma unroll
    for (int ct=0;ct<2;ct++){
      #pragma unroll
      for (int ks=0;ks<2;ks++){
        short8 t1v, t2v;
        #pragma unroll
        for (int jj=0;jj<8;jj++){
          t1v[jj] = (short)El[ks*32+fg*8+jj][ct*16+fr];
          t2v[jj] = (short)Ell[ks*32+fg*8+jj][ct*16+fr];
        }
        eb[ct][ks]=t1v; ebl[ct][ks]=t2v;
      }
    }
    #pragma unroll
    for (int it=0;it<2;it++){
      #pragma unroll
      for (int ct=0;ct<2;ct++){
        #pragma unroll
        for (int ks=0;ks<2;ks++){
          sc[it][ct] = __builtin_amdgcn_mfma_f32_16x16x32_bf16(ka[it][ks], eb[ct][ks],  sc[it][ct],0,0,0);
          sc[it][ct] = __builtin_amdgcn_mfma_f32_16x16x32_bf16(ka[it][ks], ebl[ct][ks], sc[it][ct],0,0,0);
        }
      }
    }
    #pragma unroll
    for (int it=0;it<2;it++){
      #pragma unroll
      for (int ct=0;ct<2;ct++){
        #pragma unroll
        for (int r=0;r<4;r++)
          Sl[it*16+fg*4+r][ct*16+fr] = sc[it][ct][r];
      }
    }
  }
}

// ---- phase C: O = Q S_entry + tril(QK^T) E ----
template<int PREC>
__global__ __launch_bounds__(64) void k_pC(unsigned short* qobuf,
                                           const unsigned short* __restrict__ kbuf,
                                           const unsigned short* __restrict__ ebuf,
                                           const void* __restrict__ SentP){
  __shared__ unsigned short Pl[64][72];
  __shared__ unsigned short Plo[64][72];
  __shared__ unsigned short El[64][40];
  const int c = blockIdx.x, bh = blockIdx.y, b=bh>>2, h=bh&3;
  const int lane=threadIdx.x, fr=lane&15, fg=lane>>4;
  const size_t base = ((size_t)b*TT + c*64)*128 + h*32;
  #pragma unroll
  for (int i=0;i<9;i++){
    *(uint4*)&Pl[lane][i*8]  = (uint4){0u,0u,0u,0u};
    *(uint4*)&Plo[lane][i*8] = (uint4){0u,0u,0u,0u};
  }
  {
    const unsigned short* er = ebuf + base + (size_t)lane*128;
    uint4 a0=*(const uint4*)(er),   a1=*(const uint4*)(er+8);
    uint4 a2=*(const uint4*)(er+16),a3=*(const uint4*)(er+24);
    *(uint4*)&El[lane][0]=a0; *(uint4*)&El[lane][8]=a1;
    *(uint4*)&El[lane][16]=a2; *(uint4*)&El[lane][24]=a3;
  }
  short8 qf[4], kf[4];
  #pragma unroll
  for (int mt=0;mt<4;mt++){
    qf[mt] = *(const short8*)(qobuf + base + (size_t)(mt*16+fr)*128 + fg*8);
    kf[mt] = *(const short8*)(kbuf  + base + (size_t)(mt*16+fr)*128 + fg*8);
  }
  #pragma unroll
  for (int mt=0;mt<4;mt++){
    #pragma unroll
    for (int nt=0;nt<4;nt++){
      if (nt>mt) continue;
      f32x4 p = (f32x4){0.f,0.f,0.f,0.f};
      p = __builtin_amdgcn_mfma_f32_16x16x32_bf16(qf[mt], kf[nt], p,0,0,0);
      #pragma unroll
      for (int r=0;r<4;r++){
        int t = mt*16+fg*4+r, s = nt*16+fr;
        float pv = p[r];
        unsigned short ph = f2b(pv);
        Pl[t][s]  = (s<=t)? ph : (unsigned short)0;
        Plo[t][s] = (s<=t)? f2b(pv - b2f(ph)) : (unsigned short)0;
      }
    }
  }
  f32x4 acc[4][2];
  #pragma unroll
  for (int mt=0;mt<4;mt++){
    #pragma unroll
    for (int ct=0;ct<2;ct++) acc[mt][ct]=(f32x4){0.f,0.f,0.f,0.f};
  }
  if (PREC){
    short8 sfh[2], sfl[2];
    #pragma unroll
    for (int ct=0;ct<2;ct++){
      const float* Sf = (const float*)SentP + ((size_t)bh*NC + c)*1024 + ct*512 + lane*8;
      float4 v0 = *(const float4*)Sf;
      float4 v1 = *(const float4*)(Sf+4);
      float sv[8] = {v0.x,v0.y,v0.z,v0.w,v1.x,v1.y,v1.z,v1.w};
      short8 hh, ll;
      #pragma unroll
      for (int jj=0;jj<8;jj++){
        unsigned short hi = f2b(sv[jj]);
        hh[jj]=(short)hi; ll[jj]=(short)f2b(sv[jj]-b2f(hi));
      }
      sfh[ct]=hh; sfl[ct]=ll;
    }
    #pragma unroll
    for (int mt=0;mt<4;mt++){
      #pragma unroll
      for (int ct=0;ct<2;ct++){
        acc[mt][ct]=__builtin_amdgcn_mfma_f32_16x16x32_bf16(qf[mt], sfh[ct], acc[mt][ct],0,0,0);
        acc[mt][ct]=__builtin_amdgcn_mfma_f32_16x16x32_bf16(qf[mt], sfl[ct], acc[mt][ct],0,0,0);
      }
    }
  } else {
    short8 sf[2];
    #pragma unroll
    for (int ct=0;ct<2;ct++)
      sf[ct] = *(const short8*)((const unsigned short*)SentP + ((size_t)bh*NC + c)*1024 + ct*512 + lane*8);
    #pragma unroll
    for (int mt=0;mt<4;mt++){
      #pragma unroll
      for (int ct=0;ct<2;ct++)
        acc[mt][ct]=__builtin_amdgcn_mfma_f32_16x16x32_bf16(qf[mt], sf[ct], acc[mt][ct],0,0,0);
    }
  }
  short8 ebf[2][2];
  #pragma unroll
  for (int ct=0;ct<2;ct++){
    #pragma unroll
    for (int ks=0;ks<2;ks++){
      short8 tmp;
      #pragma unroll
      for (int jj=0;jj<8;jj++) tmp[jj]=(short)El[ks*32+fg*8+jj][ct*16+fr];
      ebf[ct][ks]=tmp;
    }
  }
  #pragma unroll
  for (int mt=0;mt<4;mt++){
    #pragma unroll
    for (int ks=0;ks<2;ks++){
      short8 pa  = *(const short8*)&Pl[mt*16+fr][ks*32+fg*8];
      short8 pal = *(const short8*)&Plo[mt*16+fr][ks*32+fg*8];
      #pragma unroll
      for (int ct=0;ct<2;ct++){
        acc[mt][ct]=__builtin_amdgcn_mfma_f32_16x16x32_bf16(pa,  ebf[ct][ks], acc[mt][ct],0,0,0);
        acc[mt][ct]=__builtin_amdgcn_mfma_f32_16x16x32_bf16(pal, ebf[ct][ks], acc[mt][ct],0,0,0);
      }
    }
  }
  #pragma unroll
  for (int mt=0;mt<4;mt++){
    #pragma unroll
    for (int ct=0;ct<2;ct++){
      #pragma unroll
      for (int r=0;r<4;r++)
        qobuf[base + (size_t)(mt*16+fg*4+r)*128 + ct*16+fr] = f2b(acc[mt][ct][r]);
    }
  }
}

// ---------------- fallback sequential scan ----------------
__global__ __launch_bounds__(64) void k_scan(const unsigned short* q, const unsigned short* k,
                                             const unsigned short* v, const float* beta,
                                             unsigned short* o){
  int b = blockIdx.x>>2, hh = blockIdx.x&3;
  int lane = threadIdx.x;
  int j = lane&31, ih = lane>>5;
  float S[16];
  #pragma unroll
  for (int m=0;m<16;m++) S[m]=0.f;
  size_t idx0 = ((size_t)b*TT*HH + hh)*dh;
  size_t bidx0 = (size_t)b*TT*HH + hh;
  const unsigned short* kp = k + idx0 + ih*16;
  const unsigned short* qp = q + idx0 + ih*16;
  for (int t=0;t<TT;t++){
    size_t ofs=(size_t)t*128;
    uint4 ka=*(const uint4*)(kp+ofs), kb=*(const uint4*)(kp+ofs+8);
    uint4 qa=*(const uint4*)(qp+ofs), qb=*(const uint4*)(qp+ofs+8);
    float kf[16], qf[16];
    kf[0]=blo(ka.x);kf[1]=bhi(ka.x);kf[2]=blo(ka.y);kf[3]=bhi(ka.y);
    kf[4]=blo(ka.z);kf[5]=bhi(ka.z);kf[6]=blo(ka.w);kf[7]=bhi(ka.w);
    kf[8]=blo(kb.x);kf[9]=bhi(kb.x);kf[10]=blo(kb.y);kf[11]=bhi(kb.y);
    kf[12]=blo(kb.z);kf[13]=bhi(kb.z);kf[14]=blo(kb.w);kf[15]=bhi(kb.w);
    qf[0]=blo(qa.x);qf[1]=bhi(qa.x);qf[2]=blo(qa.y);qf[3]=bhi(qa.y);
    qf[4]=blo(qa.z);qf[5]=bhi(qa.z);qf[6]=blo(qa.w);qf[7]=bhi(qa.w);
    qf[8]=blo(qb.x);qf[9]=bhi(qb.x);qf[10]=blo(qb.y);qf[11]=bhi(qb.y);
    qf[12]=blo(qb.z);qf[13]=bhi(qb.z);qf[14]=blo(qb.w);qf[15]=bhi(qb.w);
    float vc = b2f(v[idx0+ofs+j]), bc = beta[bidx0+(size_t)t*4];
    float p0=0,p1=0,p2=0,p3=0;
    #pragma unroll
    for (int m=0;m<4;m++){
      p0 += S[m]*kf[m]; p1 += S[m+4]*kf[m+4]; p2 += S[m+8]*kf[m+8]; p3 += S[m+12]*kf[m+12];
    }
    float p = (p0+p1)+(p2+p3);
    p += __shfl_xor(p, 32, 64);
    float err = (vc - p)*bc;
    float o0=0,o1=0,o2=0,o3=0;
    #pragma unroll
    for (int m=0;m<4;m++){
      S[m]    += kf[m]*err;     o0 += S[m]*qf[m];
      S[m+4]  += kf[m+4]*err;   o1 += S[m+4]*qf[m+4];
      S[m+8]  += kf[m+8]*err;   o2 += S[m+8]*qf[m+8];
      S[m+12] += kf[m+12]*err;  o3 += S[m+12]*qf[m+12];
    }
    float oo = (o0+o1)+(o2+o3);
    oo += __shfl_xor(oo, 32, 64);
    if (ih==0) o[idx0 + ofs + j] = f2b(oo);
  }
}

// ---------------- o = rms(o, hnw)*silu(gate) ----------------
__global__ __launch_bounds__(256) void k_ogate(const unsigned short* __restrict__ o, const unsigned short* __restrict__ gate,
                                               const float* __restrict__ hnwl, unsigned short* __restrict__ tmp){
  int tid=threadIdx.x;
  size_t bt = (size_t)blockIdx.x*2 + (tid>>7);
  int c = tid&127;
  size_t i = bt*DD + c;
  float ov = b2f(o[i]);
  float ss = ov*ov;
  #pragma unroll
  for (int m=1;m<32;m<<=1) ss += __shfl_xor(ss,m,64);
  float r = rsqrtf(ss*(1.0f/32.0f)+1e-5f);
  float g = b2f(gate[i]);
  tmp[i] = f2b(ov*r*hnwl[c&31]*siluf(g));
}

extern "C" void kernel_launch(void* const* d_in, const int* in_sizes, int n_in,
                              void* d_out, int out_size, void* d_ws, size_t ws_size,
                              hipStream_t stream){
  const int*   x   = (const int*)d_in[0];
  const float* emb = (const float*)d_in[1];
  const float* qw  = (const float*)d_in[2];
  const float* kw  = (const float*)d_in[3];
  const float* vw  = (const float*)d_in[4];
  const float* qcw = (const float*)d_in[5];
  const float* qcb = (const float*)d_in[6];
  const float* kcw = (const float*)d_in[7];
  const float* kcb = (const float*)d_in[8];
  const float* vcw = (const float*)d_in[9];
  const float* vcb = (const float*)d_in[10];
  const float* ow  = (const float*)d_in[11];
  const float* gw  = (const float*)d_in[12];
  const float* bw  = (const float*)d_in[13];
  const float* hnw = (const float*)d_in[14];
  const float* n1w = (const float*)d_in[15];
  const float* n2w = (const float*)d_in[16];
  const float* m1w = (const float*)d_in[17];
  const float* m2w = (const float*)d_in[18];
  const float* fnw = (const float*)d_in[19];
  const float* hw  = (const float*)d_in[20];

  // ws layout: h | hn | A | B | C | beta | halo | U | Sent(f32 or bf16)
  char* ws = (char*)d_ws;
  size_t off = 0;
  float* h             = (float*)(ws+off);          off += (size_t)MM*DD*4;
  unsigned short* hn   = (unsigned short*)(ws+off); off += (size_t)MM*DD*2;
  unsigned short* A    = (unsigned short*)(ws+off); off += (size_t)MM*DD*2;
  unsigned short* B    = (unsigned short*)(ws+off); off += (size_t)MM*DD*2;
  unsigned short* C    = (unsigned short*)(ws+off); off += (size_t)MM*DD*2;
  float* beta          = (float*)(ws+off);          off += (size_t)MM*HH*4;
  unsigned short* halo = (unsigned short*)(ws+off); off += (size_t)NCHUNK*9*128*2;
  unsigned short* U    = (unsigned short*)(ws+off); off += (size_t)MM*DD*2;
  void* SentP          = (void*)(ws+off);
  const size_t NEED1 = off + (size_t)8192*1024*4;   // f32 Sent
  const size_t NEED0 = off + (size_t)8192*1024*2;   // bf16 Sent
  unsigned short* t1   = A;
  const int mode = (ws_size >= NEED1) ? 1 : (ws_size >= NEED0) ? 0 : -1;

  k_embed<<<MM*DD/256, 256, 0, stream>>>(x, emb, h);
  for (int l=0;l<LL;l++){
    k_rms<<<MM/4,256,0,stream>>>(h, n1w + l*DD, hn);
    k_gemm<2,0,0><<<dim3(MM/128,1),256,0,stream>>>(hn, qw + l*DD*DD, A, 128, 128);
    k_gemm<2,0,0><<<dim3(MM/128,1),256,0,stream>>>(hn, kw + l*DD*DD, B, 128, 128);
    k_gemm<2,0,0><<<dim3(MM/128,1),256,0,stream>>>(hn, vw + l*DD*DD, C, 128, 128);
    k_beta<<<MM/64,256,0,stream>>>(hn, bw + l*HH*DD, beta);
    k_halo<<<NCHUNK*9*128/256,256,0,stream>>>(A, B, C, halo);
    k_conv_ip<<<dim3(NCHUNK,3),256,0,stream>>>(A, B, C,
                                  qcw+l*DD*4, qcb+l*DD, kcw+l*DD*4, kcb+l*DD, vcw+l*DD*4, vcb+l*DD,
                                  halo);
    if (mode >= 0){
      k_pA<<<dim3(NC, BB*HH), 256, 0, stream>>>(B, C, beta, U);
      if (mode==1){
        k_pB<1><<<BB*HH, 64, 0, stream>>>(B, C, U, SentP);
        k_pC<1><<<dim3(NC, BB*HH), 64, 0, stream>>>(A, B, C, SentP);
      } else {
        k_pB<0><<<BB*HH, 64, 0, stream>>>(B, C, U, SentP);
        k_pC<0><<<dim3(NC, BB*HH), 64, 0, stream>>>(A, B, C, SentP);
      }
    } else {
      k_scan<<<BB*HH,64,0,stream>>>(A, B, C, beta, A);
    }
    k_gemm<2,0,0><<<dim3(MM/128,1),256,0,stream>>>(hn, gw + l*DD*DD, C, 128, 128);
    k_ogate<<<MM/2,256,0,stream>>>(A, C, hnw+l*dh, B);
    k_gemm<2,0,1><<<dim3(MM/128,1),256,0,stream>>>(B, ow + l*DD*DD, h, 128, 128);
    k_rms<<<MM/4,256,0,stream>>>(h, n2w + l*DD, hn);
    k_gemm<2,1,0><<<dim3(MM/128,2),256,0,stream>>>(hn, m1w + l*2*DD*DD, t1, 256, 128);
    k_gemm<2,0,1><<<dim3(MM/128,1),256,0,stream>>>(t1, m2w + l*2*DD*DD, h, 128, 256);
  }
  k_rms<<<MM/4,256,0,stream>>>(h, fnw, hn);
  k_headm<<<MM/128,256,0,stream>>>(hn, hw, (float*)d_out);
}

// Round 10
// 2717.381 us; speedup vs baseline: 2.6874x; 1.0419x over previous
//
#include <hip/hip_runtime.h>
#include <hip/hip_bf16.h>
#include <math.h>

#define BB 32
#define TT 4096
#define DD 128
#define HH 4
#define dh 32
#define VV 33
#define LL 4
#define MM (BB*TT)   // 131072 rows
#define NCHUNK (MM/128)  // 1024
#define NC 64        // delta chunks per (b,h): TT/64

typedef short short8 __attribute__((ext_vector_type(8)));
typedef float f32x4 __attribute__((ext_vector_type(4)));

__device__ __forceinline__ float b2f(unsigned short u){
  union{float f; unsigned int x;} v; v.x = ((unsigned int)u)<<16; return v.f;
}
__device__ __forceinline__ unsigned short f2b(float f){
  union{float f; unsigned int x;} v; v.f=f;
  unsigned int r = v.x + 0x7fffu + ((v.x>>16)&1u);
  return (unsigned short)(r>>16);
}
__device__ __forceinline__ float blo(unsigned int u){ union{float f;unsigned int x;}v; v.x=u<<16; return v.f;}
__device__ __forceinline__ float bhi(unsigned int u){ union{float f;unsigned int x;}v; v.x=u&0xffff0000u; return v.f;}
__device__ __forceinline__ float siluf(float x){ return x/(1.0f+expf(-x)); }

// ---------------- embedding ----------------
__global__ __launch_bounds__(256) void k_embed(const int* __restrict__ x, const float* __restrict__ emb,
                                               float* __restrict__ h){
  int i = blockIdx.x*256 + threadIdx.x;
  int bt = i>>7, c = i&127;
  h[i] = emb[x[bt]*DD + c];
}

// ---------------- rms norm ----------------
__global__ __launch_bounds__(256) void k_rms(const float* __restrict__ src, const float* __restrict__ w,
                                             unsigned short* __restrict__ dst){
  int row = blockIdx.x*4 + (threadIdx.x>>6);
  int lane = threadIdx.x&63;
  const float2 xv = *(const float2*)(src + (size_t)row*DD + lane*2);
  float ss = xv.x*xv.x + xv.y*xv.y;
  #pragma unroll
  for (int m=1;m<64;m<<=1) ss += __shfl_xor(ss,m,64);
  float sc = rsqrtf(ss*(1.0f/128.0f)+1e-5f);
  const float2 wv = *(const float2*)(w + lane*2);
  unsigned int o = ((unsigned int)f2b(xv.y*sc*wv.y)<<16) | (unsigned int)f2b(xv.x*sc*wv.x);
  *(unsigned int*)(dst + (size_t)row*DD + lane*2) = o;
}

// ---------------- MFMA GEMM, panel-looped ----------------
template<int NP, int ACT, int OUTADD>
__global__ __launch_bounds__(256) void k_gemm(const unsigned short* __restrict__ A,
                                              const float* __restrict__ W,
                                              void* __restrict__ outp, int N, int K){
  __shared__ __align__(16) unsigned short As[128*128];
  __shared__ __align__(16) unsigned short Ws[64*128];
  const int tid = threadIdx.x;
  const int lane = tid & 63, wave = tid >> 6;
  const int row0 = blockIdx.x*128, colbase = blockIdx.y*(64*NP);
  const int wr0 = (wave&1)*64, wc0 = (wave>>1)*32;
  const int fr = lane & 15, fq = lane >> 4;
  f32x4 acc[NP][4][2];
  #pragma unroll
  for (int p=0;p<NP;p++)
    #pragma unroll
    for (int m=0;m<4;m++)
      #pragma unroll
      for (int n=0;n<2;n++) acc[p][m][n] = (f32x4){0.f,0.f,0.f,0.f};

  for (int kc=0; kc<K; kc+=128){
    #pragma unroll
    for (int ii=0; ii<8; ++ii){
      int flat = tid + ii*256;
      int r = flat>>4, g = flat&15;
      uint4 gv = *(const uint4*)(A + (size_t)(row0+r)*K + kc + g*8);
      *(uint4*)&As[r*128 + ((g^(r&7))<<3)] = gv;
    }
    #pragma unroll
    for (int p=0;p<NP;p++){
      const int col0 = colbase + p*64;
      #pragma unroll
      for (int ii=0; ii<8; ++ii){
        int flat = tid + ii*256;
        int n = flat>>5, q4 = flat&31;
        float4 wv = *(const float4*)(W + (size_t)(col0+n)*K + kc + q4*4);
        uint2 pk;
        pk.x = (unsigned int)f2b(wv.x) | ((unsigned int)f2b(wv.y)<<16);
        pk.y = (unsigned int)f2b(wv.z) | ((unsigned int)f2b(wv.w)<<16);
        int dst = n*128 + ((((q4>>1)^(n&7))<<3) | ((q4&1)<<2));
        *(uint2*)&Ws[dst] = pk;
      }
      __syncthreads();
      #pragma unroll
      for (int ks=0; ks<4; ++ks){
        int gg = ks*4 + fq;
        short8 a[4], b[2];
        #pragma unroll
        for (int m=0;m<4;m++){
          int row = wr0 + m*16 + fr;
          a[m] = *(const short8*)&As[row*128 + ((gg^(row&7))<<3)];
        }
        #pragma unroll
        for (int n=0;n<2;n++){
          int col = wc0 + n*16 + fr;
          b[n] = *(const short8*)&Ws[col*128 + ((gg^(col&7))<<3)];
        }
        #pragma unroll
        for (int m=0;m<4;m++){
          #pragma unroll
          for (int n=0;n<2;n++)
            acc[p][m][n] = __builtin_amdgcn_mfma_f32_16x16x32_bf16(a[m], b[n], acc[p][m][n], 0, 0, 0);
        }
      }
      __syncthreads();
    }
  }

  #pragma unroll
  for (int p=0;p<NP;p++){
    const int col0 = colbase + p*64;
    if (OUTADD){
      float* O = (float*)outp;
      #pragma unroll
      for (int m=0;m<4;m++){
        #pragma unroll
        for (int n=0;n<2;n++){
          int ccol = col0 + wc0 + n*16 + fr;
          #pragma unroll
          for (int r=0;r<4;r++){
            int rrow = row0 + wr0 + m*16 + fq*4 + r;
            O[(size_t)rrow*N + ccol] += acc[p][m][n][r];
          }
        }
      }
    } else {
      unsigned short* O = (unsigned short*)outp;
      #pragma unroll
      for (int m=0;m<4;m++){
        #pragma unroll
        for (int n=0;n<2;n++){
          int ccol = col0 + wc0 + n*16 + fr;
          #pragma unroll
          for (int r=0;r<4;r++){
            int rrow = row0 + wr0 + m*16 + fq*4 + r;
            float vv = acc[p][m][n][r];
            if (ACT) vv = siluf(vv);
            O[(size_t)rrow*N + ccol] = f2b(vv);
          }
        }
      }
    }
  }
}

// ---------------- fused q/k/v projections: A staged once, 3 weights x 2 panels ----------------
__global__ __launch_bounds__(256) void k_qkv(const unsigned short* __restrict__ Ain,
                                             const float* __restrict__ qw,
                                             const float* __restrict__ kw,
                                             const float* __restrict__ vw,
                                             unsigned short* __restrict__ Oq,
                                             unsigned short* __restrict__ Ok,
                                             unsigned short* __restrict__ Ov){
  __shared__ __align__(16) unsigned short As[128*128];
  __shared__ __align__(16) unsigned short Ws[64*128];
  const int tid = threadIdx.x;
  const int lane = tid & 63, wave = tid >> 6;
  const int row0 = blockIdx.x*128;
  const int wr0 = (wave&1)*64, wc0 = (wave>>1)*32;
  const int fr = lane & 15, fq = lane >> 4;

  #pragma unroll
  for (int ii=0; ii<8; ++ii){
    int flat = tid + ii*256;
    int r = flat>>4, g = flat&15;
    uint4 gv = *(const uint4*)(Ain + (size_t)(row0+r)*DD + g*8);
    *(uint4*)&As[r*128 + ((g^(r&7))<<3)] = gv;
  }
  for (int t=0;t<3;t++){
    const float* W = (t==0)?qw:(t==1)?kw:vw;
    unsigned short* O = (t==0)?Oq:(t==1)?Ok:Ov;
    for (int p=0;p<2;p++){
      const int col0 = p*64;
      #pragma unroll
      for (int ii=0; ii<8; ++ii){
        int flat = tid + ii*256;
        int n = flat>>5, q4 = flat&31;
        float4 wv = *(const float4*)(W + (size_t)(col0+n)*DD + q4*4);
        uint2 pk;
        pk.x = (unsigned int)f2b(wv.x) | ((unsigned int)f2b(wv.y)<<16);
        pk.y = (unsigned int)f2b(wv.z) | ((unsigned int)f2b(wv.w)<<16);
        int dst = n*128 + ((((q4>>1)^(n&7))<<3) | ((q4&1)<<2));
        *(uint2*)&Ws[dst] = pk;
      }
      __syncthreads();
      f32x4 acc[4][2];
      #pragma unroll
      for (int m=0;m<4;m++)
        #pragma unroll
        for (int n=0;n<2;n++) acc[m][n] = (f32x4){0.f,0.f,0.f,0.f};
      #pragma unroll
      for (int ks=0; ks<4; ++ks){
        int gg = ks*4 + fq;
        short8 a[4], b[2];
        #pragma unroll
        for (int m=0;m<4;m++){
          int row = wr0 + m*16 + fr;
          a[m] = *(const short8*)&As[row*128 + ((gg^(row&7))<<3)];
        }
        #pragma unroll
        for (int n=0;n<2;n++){
          int col = wc0 + n*16 + fr;
          b[n] = *(const short8*)&Ws[col*128 + ((gg^(col&7))<<3)];
        }
        #pragma unroll
        for (int m=0;m<4;m++){
          #pragma unroll
          for (int n=0;n<2;n++)
            acc[m][n] = __builtin_amdgcn_mfma_f32_16x16x32_bf16(a[m], b[n], acc[m][n], 0, 0, 0);
        }
      }
      __syncthreads();
      #pragma unroll
      for (int m=0;m<4;m++){
        #pragma unroll
        for (int n=0;n<2;n++){
          int ccol = col0 + wc0 + n*16 + fr;
          #pragma unroll
          for (int r=0;r<4;r++){
            int rrow = row0 + wr0 + m*16 + fq*4 + r;
            O[(size_t)rrow*DD + ccol] = f2b(acc[m][n][r]);
          }
        }
      }
    }
  }
}

// ---------------- MFMA head: out[M,33] ----------------
__global__ __launch_bounds__(256) void k_headm(const unsigned short* __restrict__ A,
                                               const float* __restrict__ W,
                                               float* __restrict__ out){
  __shared__ __align__(16) unsigned short As[128*128];
  __shared__ __align__(16) unsigned short Ws[64*128];
  const int tid = threadIdx.x;
  const int lane = tid & 63, wave = tid >> 6;
  const int row0 = blockIdx.x*128;
  const int wr0 = (wave&1)*64, wc0 = (wave>>1)*32;
  const int fr = lane & 15, fq = lane >> 4;
  f32x4 acc[4][2];
  #pragma unroll
  for (int m=0;m<4;m++)
    #pragma unroll
    for (int n=0;n<2;n++) acc[m][n] = (f32x4){0.f,0.f,0.f,0.f};

  #pragma unroll
  for (int ii=0; ii<8; ++ii){
    int flat = tid + ii*256;
    int r = flat>>4, g = flat&15;
    uint4 gv = *(const uint4*)(A + (size_t)(row0+r)*DD + g*8);
    *(uint4*)&As[r*128 + ((g^(r&7))<<3)] = gv;
  }
  #pragma unroll
  for (int ii=0; ii<8; ++ii){
    int flat = tid + ii*256;
    int n = flat>>5, q4 = flat&31;
    float4 wv = (n < VV) ? *(const float4*)(W + (size_t)n*DD + q4*4)
                         : (float4){0.f,0.f,0.f,0.f};
    uint2 pk;
    pk.x = (unsigned int)f2b(wv.x) | ((unsigned int)f2b(wv.y)<<16);
    pk.y = (unsigned int)f2b(wv.z) | ((unsigned int)f2b(wv.w)<<16);
    int dst = n*128 + ((((q4>>1)^(n&7))<<3) | ((q4&1)<<2));
    *(uint2*)&Ws[dst] = pk;
  }
  __syncthreads();
  #pragma unroll
  for (int ks=0; ks<4; ++ks){
    int gg = ks*4 + fq;
    short8 a[4], b[2];
    #pragma unroll
    for (int m=0;m<4;m++){
      int row = wr0 + m*16 + fr;
      a[m] = *(const short8*)&As[row*128 + ((gg^(row&7))<<3)];
    }
    #pragma unroll
    for (int n=0;n<2;n++){
      int col = wc0 + n*16 + fr;
      b[n] = *(const short8*)&Ws[col*128 + ((gg^(col&7))<<3)];
    }
    #pragma unroll
    for (int m=0;m<4;m++){
      #pragma unroll
      for (int n=0;n<2;n++)
        acc[m][n] = __builtin_amdgcn_mfma_f32_16x16x32_bf16(a[m], b[n], acc[m][n], 0, 0, 0);
    }
  }
  #pragma unroll
  for (int m=0;m<4;m++){
    #pragma unroll
    for (int n=0;n<2;n++){
      int ccol = wc0 + n*16 + fr;
      if (ccol < VV){
        #pragma unroll
        for (int r=0;r<4;r++){
          int rrow = row0 + wr0 + m*16 + fq*4 + r;
          out[(size_t)rrow*VV + ccol] = acc[m][n][r];
        }
      }
    }
  }
}

// ---------------- beta = sigmoid(hn @ bw^T), N=4 ----------------
__global__ __launch_bounds__(256) void k_beta(const unsigned short* __restrict__ hn,
                                              const float* __restrict__ bwl, float* __restrict__ beta){
  __shared__ unsigned short As[64*128];
  int tid = threadIdx.x; int row0 = blockIdx.x*64;
  #pragma unroll
  for (int ii=0;ii<4;ii++){
    int flat = tid + ii*256;
    int r = flat>>4, v16 = flat&15;
    *(uint4*)&As[r*128 + v16*8] = *(const uint4*)(hn + (size_t)(row0+r)*DD + v16*8);
  }
  __syncthreads();
  int r = tid>>2, n = tid&3;
  const float* wr = bwl + n*DD;
  const unsigned short* ar = &As[r*128];
  float s = 0.f;
  #pragma unroll
  for (int k=0;k<128;k+=8){
    uint4 a = *(const uint4*)(ar + k);
    float4 wa = *(const float4*)(wr + k);
    float4 wb = *(const float4*)(wr + k + 4);
    s += blo(a.x)*wa.x + bhi(a.x)*wa.y + blo(a.y)*wa.z + bhi(a.y)*wa.w;
    s += blo(a.z)*wb.x + bhi(a.z)*wb.y + blo(a.w)*wb.z + bhi(a.w)*wb.w;
  }
  beta[(size_t)(row0+r)*HH + n] = 1.0f/(1.0f+expf(-s));
}

// ---------------- halo save ----------------
__global__ __launch_bounds__(256) void k_halo(const unsigned short* __restrict__ A,
                                              const unsigned short* __restrict__ B,
                                              const unsigned short* __restrict__ C,
                                              unsigned short* __restrict__ halo){
  int i = blockIdx.x*256 + threadIdx.x;
  int ch = i & 127;
  int rt = i >> 7;
  int r3 = rt % 3;
  int tn = (rt/3) % 3;
  int ck = rt / 9;
  unsigned short v = 0;
  if ((ck & 31) != 0){
    const unsigned short* X = (tn==0) ? A : (tn==1) ? B : C;
    v = X[((size_t)ck*128 - 3 + r3)*DD + ch];
  }
  halo[(size_t)i] = v;
}

// ---------------- in-place causal conv(4)+silu(+l2n) ----------------
__global__ __launch_bounds__(256) void k_conv_ip(
    unsigned short* __restrict__ A, unsigned short* __restrict__ B, unsigned short* __restrict__ C,
    const float* __restrict__ qcw, const float* __restrict__ qcb,
    const float* __restrict__ kcw, const float* __restrict__ kcb,
    const float* __restrict__ vcw, const float* __restrict__ vcb,
    const unsigned short* __restrict__ halo){
  __shared__ __align__(16) unsigned short Xs[131*128];
  const int tid = threadIdx.x;
  const int ck = blockIdx.x, tn = blockIdx.y;
  unsigned short* X = (tn==0) ? A : (tn==1) ? B : C;
  const float* w = (tn==0) ? qcw : (tn==1) ? kcw : vcw;
  const float* bi = (tn==0) ? qcb : (tn==1) ? kcb : vcb;

  if (tid < 48){
    int lr = tid>>4, c16 = tid&15;
    *(uint4*)&Xs[lr*128 + c16*8] = *(const uint4*)&halo[((size_t)(ck*3+tn)*3 + lr)*128 + c16*8];
  }
  #pragma unroll
  for (int ii=0; ii<8; ++ii){
    int flat = tid + ii*256;
    int r = flat>>4, c16 = flat&15;
    *(uint4*)&Xs[(3+r)*128 + c16*8] = *(const uint4*)&X[((size_t)ck*128 + r)*DD + c16*8];
  }
  __syncthreads();

  const int rh = tid>>7, c = tid&127;
  float w0=w[c*4+0], w1=w[c*4+1], w2=w[c*4+2], w3=w[c*4+3];
  float bc = bi[c];
  #pragma unroll 2
  for (int rr=0; rr<64; ++rr){
    int row = rr*2 + rh;
    float y = bc + w0*b2f(Xs[(row+0)*128+c]) + w1*b2f(Xs[(row+1)*128+c])
                 + w2*b2f(Xs[(row+2)*128+c]) + w3*b2f(Xs[(row+3)*128+c]);
    y = siluf(y);
    if (tn < 2){
      float s = y*y;
      #pragma unroll
      for (int m=1;m<32;m<<=1) s += __shfl_xor(s,m,64);
      y *= rsqrtf(s + 1e-6f);
      if (tn==0) y *= 0.17677669529663687f;
    }
    X[((size_t)ck*128 + row)*DD + c] = f2b(y);
  }
}

// ======================= chunked delta-rule (WY form) =======================
// ---- phase A (v3): 4-wave cooperative blocked forward substitution ----
__global__ __launch_bounds__(256) void k_pA(const unsigned short* __restrict__ kbuf,
                                            unsigned short* vwbuf,
                                            const float* __restrict__ betab,
                                            unsigned short* __restrict__ Ubuf){
  __shared__ float Abt[64][68];
  __shared__ float sol[64][72];
  __shared__ float bs[64];
  const int c = blockIdx.x, bh = blockIdx.y;
  const int b = bh>>2, h = bh&3;
  const int tid = threadIdx.x;
  const int wave = tid>>6, lane = tid&63;
  const int fr = lane&15, fg = lane>>4;
  const size_t base = ((size_t)b*TT + c*64)*128 + h*32;
  const size_t bbase = ((size_t)b*TT + c*64)*4 + h;
  const size_t ub = ((size_t)bh*NC + c)*2048;

  if (tid < 64) bs[tid] = betab[bbase + (size_t)tid*4];

  short8 kA  = *(const short8*)(kbuf + base + (size_t)(wave*16+fr)*128 + fg*8);
  short8 kB0 = *(const short8*)(kbuf + base + (size_t)( 0+fr)*128 + fg*8);
  short8 kB1 = *(const short8*)(kbuf + base + (size_t)(16+fr)*128 + fg*8);
  short8 kB2 = *(const short8*)(kbuf + base + (size_t)(32+fr)*128 + fg*8);
  short8 kB3 = *(const short8*)(kbuf + base + (size_t)(48+fr)*128 + fg*8);
  __syncthreads();

  {
    float4 bsv = *(const float4*)&bs[wave*16 + fg*4];
    f32x4 a;
    #define BUILD(nt, kB) if (wave >= nt){ \
      a = (f32x4){0.f,0.f,0.f,0.f}; \
      a = __builtin_amdgcn_mfma_f32_16x16x32_bf16(kA, kB, a, 0,0,0); \
      Abt[nt*16+fr][wave*16+fg*4+0] = a[0]*bsv.x; \
      Abt[nt*16+fr][wave*16+fg*4+1] = a[1]*bsv.y; \
      Abt[nt*16+fr][wave*16+fg*4+2] = a[2]*bsv.z; \
      Abt[nt*16+fr][wave*16+fg*4+3] = a[3]*bsv.w; }
    BUILD(0, kB0) BUILD(1, kB1) BUILD(2, kB2) BUILD(3, kB3)
    #undef BUILD
  }

  const unsigned short* xp = ((lane<32)? (const unsigned short*)vwbuf : kbuf) + base + (lane&31);
  float racc[16];
  #pragma unroll
  for (int r=0;r<16;r++)
    racc[r] = b2f(xp[(size_t)(wave*16+r)*128]) * bs[wave*16+r];

  #pragma unroll
  for (int p=0;p<4;p++){
    if (wave == p){
      #pragma unroll
      for (int r=0;r<16;r++){
        float w_ = racc[r];
        sol[p*16+r][lane] = w_;
        #pragma unroll
        for (int r2=r+1;r2<16;r2++)
          racc[r2] -= Abt[p*16+r][p*16+r2] * w_;
      }
    }
    __syncthreads();
    if (wave > p){
      #pragma unroll
      for (int s16=0;s16<16;s16++){
        float w_ = sol[p*16+s16][lane];
        #pragma unroll
        for (int r=0;r<16;r++)
          racc[r] -= Abt[p*16+s16][wave*16+r] * w_;
      }
    }
    __syncthreads();
  }

  {
    int row = tid>>2, qt = tid&3;
    if (qt < 2){
      #pragma unroll
      for (int i=0;i<8;i++){
        int col = qt*16 + i*2;
        unsigned int pk = (unsigned int)f2b(sol[row][col]) | ((unsigned int)f2b(sol[row][col+1])<<16);
        *(unsigned int*)(vwbuf + base + (size_t)row*128 + col) = pk;
      }
    } else {
      #pragma unroll
      for (int i=0;i<8;i++){
        int col = (qt-2)*16 + i*2;
        unsigned int pk = (unsigned int)f2b(sol[row][32+col]) | ((unsigned int)f2b(sol[row][33+col])<<16);
        *(unsigned int*)(Ubuf + ub + row*32 + col) = pk;
      }
    }
  }
}

// ---- phase B (v2): 4-wave cooperative, serial over 64 chunks, register prefetch ----
// wave w: computes E row-tile mt=w, and S-quadrant (it=w>>1, ct=w&1).
template<int PREC>
__global__ __launch_bounds__(256) void k_pB(const unsigned short* __restrict__ kbuf,
                                           unsigned short* webuf,
                                           const unsigned short* __restrict__ Ubuf,
                                           void* __restrict__ SentP){
  __shared__ float Sl[32][33];
  __shared__ unsigned short Kl[64][40];
  __shared__ unsigned short El[64][40];   // holds W (staged), then E hi
  __shared__ unsigned short Ell[64][40];  // E lo
  const int bh = blockIdx.x, b = bh>>2, h = bh&3;
  const int tid = threadIdx.x, wave = tid>>6, lane = tid&63;
  const int fr = lane&15, fg = lane>>4;
  const int srow = tid>>2, sq = tid&3;    // staging: thread stages row srow, 8-short quarter sq
  const int it = wave>>1, ctw = wave&1;
  for (int i=tid; i<32*33; i+=256) ((float*)Sl)[i] = 0.f;
  f32x4 sc = (f32x4){0.f,0.f,0.f,0.f};

  const size_t base0 = ((size_t)b*TT)*128 + h*32;
  const size_t ub0 = (size_t)bh*NC*2048;
  uint4 pK = *(const uint4*)(kbuf  + base0 + (size_t)srow*128 + sq*8);
  uint4 pW = *(const uint4*)(webuf + base0 + (size_t)srow*128 + sq*8);
  uint4 pU = *(const uint4*)(Ubuf + ub0 + (size_t)(wave*16+fr)*32 + fg*8);

  for (int c=0;c<NC;c++){
    const size_t cbase = ((size_t)b*TT + c*64)*128 + h*32;
    __syncthreads();                         // prev chunk's LDS reads done
    *(uint4*)&Kl[srow][sq*8] = pK;
    *(uint4*)&El[srow][sq*8] = pW;           // W staged into El
    short8 uf; { union{uint4 u; short8 s;} cv; cv.u = pU; uf = cv.s; }
    __syncthreads();                         // staged visible
    if (c+1 < NC){                           // prefetch next chunk (latency hides under compute)
      pK = *(const uint4*)(kbuf  + cbase + 64*128 + (size_t)srow*128 + sq*8);
      pW = *(const uint4*)(webuf + cbase + 64*128 + (size_t)srow*128 + sq*8);
      pU = *(const uint4*)(Ubuf + ub0 + (size_t)(c+1)*2048 + (size_t)(wave*16+fr)*32 + fg*8);
    }
    // S B-frags (hi+lo of -S), all waves
    short8 sb[2], sbl[2];
    #pragma unroll
    for (int ct=0;ct<2;ct++){
      #pragma unroll
      for (int jj=0;jj<8;jj++){
        float sv = Sl[fg*8+jj][ct*16+fr];
        float nv = -sv;
        unsigned short hi = f2b(nv);
        sb[ct][jj] = (short)hi;
        sbl[ct][jj] = (short)f2b(nv - b2f(hi));
      }
    }
    if (wave==0){                            // S_entry store
      if (PREC){
        #pragma unroll
        for (int ct=0;ct<2;ct++){
          float* Sf = (float*)SentP + ((size_t)bh*NC + c)*1024 + ct*512 + lane*8;
          #pragma unroll
          for (int jj=0;jj<8;jj++) Sf[jj] = Sl[fg*8+jj][ct*16+fr];
        }
      } else {
        #pragma unroll
        for (int ct=0;ct<2;ct++){
          unsigned short* Sf = (unsigned short*)SentP + ((size_t)bh*NC + c)*1024 + ct*512 + lane*8;
          #pragma unroll
          for (int jj=0;jj<8;jj++) Sf[jj] = f2b(Sl[fg*8+jj][ct*16+fr]);
        }
      }
    }
    // E = W + U*(-S_hi) + U*(-S_lo), own row-tile mt=wave
    f32x4 acc[2];
    #pragma unroll
    for (int ct=0;ct<2;ct++){
      #pragma unroll
      for (int r=0;r<4;r++)
        acc[ct][r] = b2f(El[wave*16+fg*4+r][ct*16+fr]);
    }
    #pragma unroll
    for (int ct=0;ct<2;ct++){
      acc[ct] = __builtin_amdgcn_mfma_f32_16x16x32_bf16(uf, sb[ct],  acc[ct],0,0,0);
      acc[ct] = __builtin_amdgcn_mfma_f32_16x16x32_bf16(uf, sbl[ct], acc[ct],0,0,0);
    }
    #pragma unroll
    for (int ct=0;ct<2;ct++){
      #pragma unroll
      for (int r=0;r<4;r++){
        float ef = acc[ct][r];
        unsigned short eh = f2b(ef);
        int t = wave*16+fg*4+r, j = ct*16+fr;
        El[t][j] = eh;
        Ell[t][j] = f2b(ef - b2f(eh));
        webuf[cbase + (size_t)t*128 + j] = eh;
      }
    }
    __syncthreads();                         // E visible
    // S += K^T (E_hi + E_lo), own quadrant (it, ctw)
    #pragma unroll
    for (int ks=0;ks<2;ks++){
      short8 ka, eb, ebl;
      #pragma unroll
      for (int jj=0;jj<8;jj++){
        ka[jj]  = (short)Kl [ks*32+fg*8+jj][it*16+fr];
        eb[jj]  = (short)El [ks*32+fg*8+jj][ctw*16+fr];
        ebl[jj] = (short)Ell[ks*32+fg*8+jj][ctw*16+fr];
      }
      sc = __builtin_amdgcn_mfma_f32_16x16x32_bf16(ka, eb,  sc,0,0,0);
      sc = __builtin_amdgcn_mfma_f32_16x16x32_bf16(ka, ebl, sc,0,0,0);
    }
    #pragma unroll
    for (int r=0;r<4;r++)
      Sl[it*16+fg*4+r][ctw*16+fr] = sc[r];
  }
}

// ---- phase C: O = Q S_entry + tril(QK^T) E ----
template<int PREC>
__global__ __launch_bounds__(64) void k_pC(unsigned short* qobuf,
                                           const unsigned short* __restrict__ kbuf,
                                           const unsigned short* __restrict__ ebuf,
                                           const void* __restrict__ SentP){
  __shared__ unsigned short Pl[64][72];
  __shared__ unsigned short Plo[64][72];
  __shared__ unsigned short El[64][40];
  const int c = blockIdx.x, bh = blockIdx.y, b=bh>>2, h=bh&3;
  const int lane=threadIdx.x, fr=lane&15, fg=lane>>4;
  const size_t base = ((size_t)b*TT + c*64)*128 + h*32;
  #pragma unroll
  for (int i=0;i<9;i++){
    *(uint4*)&Pl[lane][i*8]  = (uint4){0u,0u,0u,0u};
    *(uint4*)&Plo[lane][i*8] = (uint4){0u,0u,0u,0u};
  }
  {
    const unsigned short* er = ebuf + base + (size_t)lane*128;
    uint4 a0=*(const uint4*)(er),   a1=*(const uint4*)(er+8);
    uint4 a2=*(const uint4*)(er+16),a3=*(const uint4*)(er+24);
    *(uint4*)&El[lane][0]=a0; *(uint4*)&El[lane][8]=a1;
    *(uint4*)&El[lane][16]=a2; *(uint4*)&El[lane][24]=a3;
  }
  short8 qf[4], kf[4];
  #pragma unroll
  for (int mt=0;mt<4;mt++){
    qf[mt] = *(const short8*)(qobuf + base + (size_t)(mt*16+fr)*128 + fg*8);
    kf[mt] = *(const short8*)(kbuf  + base + (size_t)(mt*16+fr)*128 + fg*8);
  }
  #pragma unroll
  for (int mt=0;mt<4;mt++){
    #pragma unroll
    for (int nt=0;nt<4;nt++){
      if (nt>mt) continue;
      f32x4 p = (f32x4){0.f,0.f,0.f,0.f};
      p = __builtin_amdgcn_mfma_f32_16x16x32_bf16(qf[mt], kf[nt], p,0,0,0);
      #pragma unroll
      for (int r=0;r<4;r++){
        int t = mt*16+fg*4+r, s = nt*16+fr;
        float pv = p[r];
        unsigned short ph = f2b(pv);
        Pl[t][s]  = (s<=t)? ph : (unsigned short)0;
        Plo[t][s] = (s<=t)? f2b(pv - b2f(ph)) : (unsigned short)0;
      }
    }
  }
  f32x4 acc[4][2];
  #pragma unroll
  for (int mt=0;mt<4;mt++){
    #pragma unroll
    for (int ct=0;ct<2;ct++) acc[mt][ct]=(f32x4){0.f,0.f,0.f,0.f};
  }
  if (PREC){
    short8 sfh[2], sfl[2];
    #pragma unroll
    for (int ct=0;ct<2;ct++){
      const float* Sf = (const float*)SentP + ((size_t)bh*NC + c)*1024 + ct*512 + lane*8;
      float4 v0 = *(const float4*)Sf;
      float4 v1 = *(const float4*)(Sf+4);
      float sv[8] = {v0.x,v0.y,v0.z,v0.w,v1.x,v1.y,v1.z,v1.w};
      short8 hh, ll;
      #pragma unroll
      for (int jj=0;jj<8;jj++){
        unsigned short hi = f2b(sv[jj]);
        hh[jj]=(short)hi; ll[jj]=(short)f2b(sv[jj]-b2f(hi));
      }
      sfh[ct]=hh; sfl[ct]=ll;
    }
    #pragma unroll
    for (int mt=0;mt<4;mt++){
      #pragma unroll
      for (int ct=0;ct<2;ct++){
        acc[mt][ct]=__builtin_amdgcn_mfma_f32_16x16x32_bf16(qf[mt], sfh[ct], acc[mt][ct],0,0,0);
        acc[mt][ct]=__builtin_amdgcn_mfma_f32_16x16x32_bf16(qf[mt], sfl[ct], acc[mt][ct],0,0,0);
      }
    }
  } else {
    short8 sf[2];
    #pragma unroll
    for (int ct=0;ct<2;ct++)
      sf[ct] = *(const short8*)((const unsigned short*)SentP + ((size_t)bh*NC + c)*1024 + ct*512 + lane*8);
    #pragma unroll
    for (int mt=0;mt<4;mt++){
      #pragma unroll
      for (int ct=0;ct<2;ct++)
        acc[mt][ct]=__builtin_amdgcn_mfma_f32_16x16x32_bf16(qf[mt], sf[ct], acc[mt][ct],0,0,0);
    }
  }
  short8 ebf[2][2];
  #pragma unroll
  for (int ct=0;ct<2;ct++){
    #pragma unroll
    for (int ks=0;ks<2;ks++){
      short8 tmp;
      #pragma unroll
      for (int jj=0;jj<8;jj++) tmp[jj]=(short)El[ks*32+fg*8+jj][ct*16+fr];
      ebf[ct][ks]=tmp;
    }
  }
  #pragma unroll
  for (int mt=0;mt<4;mt++){
    #pragma unroll
    for (int ks=0;ks<2;ks++){
      short8 pa  = *(const short8*)&Pl[mt*16+fr][ks*32+fg*8];
      short8 pal = *(const short8*)&Plo[mt*16+fr][ks*32+fg*8];
      #pragma unroll
      for (int ct=0;ct<2;ct++){
        acc[mt][ct]=__builtin_amdgcn_mfma_f32_16x16x32_bf16(pa,  ebf[ct][ks], acc[mt][ct],0,0,0);
        acc[mt][ct]=__builtin_amdgcn_mfma_f32_16x16x32_bf16(pal, ebf[ct][ks], acc[mt][ct],0,0,0);
      }
    }
  }
  #pragma unroll
  for (int mt=0;mt<4;mt++){
    #pragma unroll
    for (int ct=0;ct<2;ct++){
      #pragma unroll
      for (int r=0;r<4;r++)
        qobuf[base + (size_t)(mt*16+fg*4+r)*128 + ct*16+fr] = f2b(acc[mt][ct][r]);
    }
  }
}

// ---------------- fallback sequential scan ----------------
__global__ __launch_bounds__(64) void k_scan(const unsigned short* q, const unsigned short* k,
                                             const unsigned short* v, const float* beta,
                                             unsigned short* o){
  int b = blockIdx.x>>2, hh = blockIdx.x&3;
  int lane = threadIdx.x;
  int j = lane&31, ih = lane>>5;
  float S[16];
  #pragma unroll
  for (int m=0;m<16;m++) S[m]=0.f;
  size_t idx0 = ((size_t)b*TT*HH + hh)*dh;
  size_t bidx0 = (size_t)b*TT*HH + hh;
  const unsigned short* kp = k + idx0 + ih*16;
  const unsigned short* qp = q + idx0 + ih*16;
  for (int t=0;t<TT;t++){
    size_t ofs=(size_t)t*128;
    uint4 ka=*(const uint4*)(kp+ofs), kb=*(const uint4*)(kp+ofs+8);
    uint4 qa=*(const uint4*)(qp+ofs), qb=*(const uint4*)(qp+ofs+8);
    float kf[16], qf[16];
    kf[0]=blo(ka.x);kf[1]=bhi(ka.x);kf[2]=blo(ka.y);kf[3]=bhi(ka.y);
    kf[4]=blo(ka.z);kf[5]=bhi(ka.z);kf[6]=blo(ka.w);kf[7]=bhi(ka.w);
    kf[8]=blo(kb.x);kf[9]=bhi(kb.x);kf[10]=blo(kb.y);kf[11]=bhi(kb.y);
    kf[12]=blo(kb.z);kf[13]=bhi(kb.z);kf[14]=blo(kb.w);kf[15]=bhi(kb.w);
    qf[0]=blo(qa.x);qf[1]=bhi(qa.x);qf[2]=blo(qa.y);qf[3]=bhi(qa.y);
    qf[4]=blo(qa.z);qf[5]=bhi(qa.z);qf[6]=blo(qa.w);qf[7]=bhi(qa.w);
    qf[8]=blo(qb.x);qf[9]=bhi(qb.x);qf[10]=blo(qb.y);qf[11]=bhi(qb.y);
    qf[12]=blo(qb.z);qf[13]=bhi(qb.z);qf[14]=blo(qb.w);qf[15]=bhi(qb.w);
    float vc = b2f(v[idx0+ofs+j]), bc = beta[bidx0+(size_t)t*4];
    float p0=0,p1=0,p2=0,p3=0;
    #pragma unroll
    for (int m=0;m<4;m++){
      p0 += S[m]*kf[m]; p1 += S[m+4]*kf[m+4]; p2 += S[m+8]*kf[m+8]; p3 += S[m+12]*kf[m+12];
    }
    float p = (p0+p1)+(p2+p3);
    p += __shfl_xor(p, 32, 64);
    float err = (vc - p)*bc;
    float o0=0,o1=0,o2=0,o3=0;
    #pragma unroll
    for (int m=0;m<4;m++){
      S[m]    += kf[m]*err;     o0 += S[m]*qf[m];
      S[m+4]  += kf[m+4]*err;   o1 += S[m+4]*qf[m+4];
      S[m+8]  += kf[m+8]*err;   o2 += S[m+8]*qf[m+8];
      S[m+12] += kf[m+12]*err;  o3 += S[m+12]*qf[m+12];
    }
    float oo = (o0+o1)+(o2+o3);
    oo += __shfl_xor(oo, 32, 64);
    if (ih==0) o[idx0 + ofs + j] = f2b(oo);
  }
}

// ---------------- o = rms(o, hnw)*silu(gate) ----------------
__global__ __launch_bounds__(256) void k_ogate(const unsigned short* __restrict__ o, const unsigned short* __restrict__ gate,
                                               const float* __restrict__ hnwl, unsigned short* __restrict__ tmp){
  int tid=threadIdx.x;
  size_t bt = (size_t)blockIdx.x*2 + (tid>>7);
  int c = tid&127;
  size_t i = bt*DD + c;
  float ov = b2f(o[i]);
  float ss = ov*ov;
  #pragma unroll
  for (int m=1;m<32;m<<=1) ss += __shfl_xor(ss,m,64);
  float r = rsqrtf(ss*(1.0f/32.0f)+1e-5f);
  float g = b2f(gate[i]);
  tmp[i] = f2b(ov*r*hnwl[c&31]*siluf(g));
}

extern "C" void kernel_launch(void* const* d_in, const int* in_sizes, int n_in,
                              void* d_out, int out_size, void* d_ws, size_t ws_size,
                              hipStream_t stream){
  const int*   x   = (const int*)d_in[0];
  const float* emb = (const float*)d_in[1];
  const float* qw  = (const float*)d_in[2];
  const float* kw  = (const float*)d_in[3];
  const float* vw  = (const float*)d_in[4];
  const float* qcw = (const float*)d_in[5];
  const float* qcb = (const float*)d_in[6];
  const float* kcw = (const float*)d_in[7];
  const float* kcb = (const float*)d_in[8];
  const float* vcw = (const float*)d_in[9];
  const float* vcb = (const float*)d_in[10];
  const float* ow  = (const float*)d_in[11];
  const float* gw  = (const float*)d_in[12];
  const float* bw  = (const float*)d_in[13];
  const float* hnw = (const float*)d_in[14];
  const float* n1w = (const float*)d_in[15];
  const float* n2w = (const float*)d_in[16];
  const float* m1w = (const float*)d_in[17];
  const float* m2w = (const float*)d_in[18];
  const float* fnw = (const float*)d_in[19];
  const float* hw  = (const float*)d_in[20];

  // ws layout: h | hn | A | B | C | beta | halo | U | Sent(f32 or bf16)
  char* ws = (char*)d_ws;
  size_t off = 0;
  float* h             = (float*)(ws+off);          off += (size_t)MM*DD*4;
  unsigned short* hn   = (unsigned short*)(ws+off); off += (size_t)MM*DD*2;
  unsigned short* A    = (unsigned short*)(ws+off); off += (size_t)MM*DD*2;
  unsigned short* B    = (unsigned short*)(ws+off); off += (size_t)MM*DD*2;
  unsigned short* C    = (unsigned short*)(ws+off); off += (size_t)MM*DD*2;
  float* beta          = (float*)(ws+off);          off += (size_t)MM*HH*4;
  unsigned short* halo = (unsigned short*)(ws+off); off += (size_t)NCHUNK*9*128*2;
  unsigned short* U    = (unsigned short*)(ws+off); off += (size_t)MM*DD*2;
  void* SentP          = (void*)(ws+off);
  const size_t NEED1 = off + (size_t)8192*1024*4;   // f32 Sent
  const size_t NEED0 = off + (size_t)8192*1024*2;   // bf16 Sent
  unsigned short* t1   = A;
  const int mode = (ws_size >= NEED1) ? 1 : (ws_size >= NEED0) ? 0 : -1;

  k_embed<<<MM*DD/256, 256, 0, stream>>>(x, emb, h);
  for (int l=0;l<LL;l++){
    k_rms<<<MM/4,256,0,stream>>>(h, n1w + l*DD, hn);
    k_qkv<<<MM/128,256,0,stream>>>(hn, qw + l*DD*DD, kw + l*DD*DD, vw + l*DD*DD, A, B, C);
    k_beta<<<MM/64,256,0,stream>>>(hn, bw + l*HH*DD, beta);
    k_halo<<<NCHUNK*9*128/256,256,0,stream>>>(A, B, C, halo);
    k_conv_ip<<<dim3(NCHUNK,3),256,0,stream>>>(A, B, C,
                                  qcw+l*DD*4, qcb+l*DD, kcw+l*DD*4, kcb+l*DD, vcw+l*DD*4, vcb+l*DD,
                                  halo);
    if (mode >= 0){
      k_pA<<<dim3(NC, BB*HH), 256, 0, stream>>>(B, C, beta, U);
      if (mode==1){
        k_pB<1><<<BB*HH, 256, 0, stream>>>(B, C, U, SentP);
        k_pC<1><<<dim3(NC, BB*HH), 64, 0, stream>>>(A, B, C, SentP);
      } else {
        k_pB<0><<<BB*HH, 256, 0, stream>>>(B, C, U, SentP);
        k_pC<0><<<dim3(NC, BB*HH), 64, 0, stream>>>(A, B, C, SentP);
      }
    } else {
      k_scan<<<BB*HH,64,0,stream>>>(A, B, C, beta, A);
    }
    k_gemm<2,0,0><<<dim3(MM/128,1),256,0,stream>>>(hn, gw + l*DD*DD, C, 128, 128);
    k_ogate<<<MM/2,256,0,stream>>>(A, C, hnw+l*dh, B);
    k_gemm<2,0,1><<<dim3(MM/128,1),256,0,stream>>>(B, ow + l*DD*DD, h, 128, 128);
    k_rms<<<MM/4,256,0,stream>>>(h, n2w + l*DD, hn);
    k_gemm<2,1,0><<<dim3(MM/128,2),256,0,stream>>>(hn, m1w + l*2*DD*DD, t1, 256, 128);
    k_gemm<2,0,1><<<dim3(MM/128,1),256,0,stream>>>(t1, m2w + l*2*DD*DD, h, 128, 256);
  }
  k_rms<<<MM/4,256,0,stream>>>(h, fnw, hn);
  k_headm<<<MM/128,256,0,stream>>>(hn, hw, (float*)d_out);
}